// Round 2
// baseline (354.759 us; speedup 1.0000x reference)
//
#include <hip/hip_runtime.h>
#include <math.h>
#include <stdint.h>

// ---------------------------------------------------------------------------
// TransformerLayer (Swin-style) on MI355X. Global tensors are FP32;
// internal compute bf16 MFMA 16x16x32 (threshold 1.4e-1 allows it).
// Shapes: B=2, H=W=128, C=128, NS=8 -> 64 windows of 256 tokens; HID=1024.
// ---------------------------------------------------------------------------

typedef unsigned short u16;
typedef __attribute__((ext_vector_type(8))) short bf16x8;   // 8 bf16 (4 VGPRs)
typedef __attribute__((ext_vector_type(4))) float f32x4;
typedef __attribute__((ext_vector_type(4))) short u16x4;

__device__ __forceinline__ u16 f2b(float f) {
    unsigned int i = __float_as_uint(f);
    unsigned int r = (i + 0x7fffu + ((i >> 16) & 1u)) >> 16;
    return (u16)r;
}

// 16B async global->LDS copy (m97-verified). LDS dest wave-uniform + lane*16.
__device__ __forceinline__ void cp16(const void* g, void* l) {
    auto* gp = reinterpret_cast<const __attribute__((address_space(1))) unsigned int*>(
        reinterpret_cast<uintptr_t>(g));
    auto* lp = reinterpret_cast<__attribute__((address_space(3))) unsigned int*>(
        reinterpret_cast<uintptr_t>(l));
    __builtin_amdgcn_global_load_lds(gp, lp, 16, 0, 0);
}

// window row (b*16384 + win*256 + t) -> source-order row (b*16384 + h*128 + w)
__device__ __forceinline__ int win_map(int gm) {
    int b = gm >> 14, rr = gm & 16383;
    int win = rr >> 8, t = rr & 255;
    int wi = win >> 3, wj = win & 7, i = t >> 4, j = t & 15;
    int h = (wi * 16 + i + 8) & 127;
    int w = (wj * 16 + j + 8) & 127;
    return (b << 14) + h * 128 + w;
}

enum { AM_PLAIN = 0, AM_WIN = 1, AM_CAT = 2 };
enum { EP_STORE = 0, EP_VT = 1, EP_GELU = 2, EP_STOREF = 3 };

// ---------------------------------------------------------------------------
// MFMA GEMM: C[M x N] = A[M x K] * Bt[N x K]^T   (m97 structure, all-bf16 ws)
// ---------------------------------------------------------------------------
template <int AMODE, int EPI>
__global__ __launch_bounds__(256, 2)
void gemm_mfma(const u16* __restrict__ A0, const u16* __restrict__ A1,
               const u16* __restrict__ Bt, void* __restrict__ Cv,
               int K, int N)
{
    __shared__ __align__(16) u16 As[128 * 32];
    __shared__ __align__(16) u16 Bs[128 * 32];

    const int tid = threadIdx.x;
    const int w = tid >> 6, lane = tid & 63;
    const int lm = lane & 15, q = lane >> 4;
    const int wm = w >> 1, wn = w & 1;
    const int m0 = blockIdx.x * 128, n0 = blockIdx.y * 128;

    size_t aoff[2], boff[2];
#pragma unroll
    for (int i = 0; i < 2; ++i) {
        int row = w * 32 + i * 16 + (lane >> 2);
        int gm = m0 + row;
        if (AMODE == AM_WIN)      aoff[i] = (size_t)win_map(gm) * 128 + (lane & 3) * 8;
        else if (AMODE == AM_CAT) aoff[i] = (size_t)gm * 128 + (lane & 3) * 8;
        else                      aoff[i] = (size_t)gm * K + (lane & 3) * 8;
        boff[i] = (size_t)(n0 + row) * K + (lane & 3) * 8;
    }

    f32x4 acc[4][4] = {};
    const int KT = K >> 5;
    for (int kt = 0; kt < KT; ++kt) {
        __syncthreads();
#pragma unroll
        for (int i = 0; i < 2; ++i) {
            const u16* ga;
            if (AMODE == AM_CAT) {
                int kk = kt * 32 + (lane & 3) * 8;
                ga = (kk < 128) ? (A0 + aoff[i] + kt * 32)
                                : (A1 + aoff[i] + kt * 32 - 128);
            } else {
                ga = A0 + aoff[i] + kt * 32;
            }
            cp16(ga, (void*)(As + (w * 32 + i * 16) * 32));
            cp16(Bt + boff[i] + kt * 32, (void*)(Bs + (w * 32 + i * 16) * 32));
        }
        __syncthreads();
        bf16x8 af[4], bfr[4];
#pragma unroll
        for (int t = 0; t < 4; ++t)
            af[t] = *(const bf16x8*)(As + (wm * 64 + t * 16 + lm) * 32 + q * 8);
#pragma unroll
        for (int t = 0; t < 4; ++t)
            bfr[t] = *(const bf16x8*)(Bs + (wn * 64 + t * 16 + lm) * 32 + q * 8);
#pragma unroll
        for (int mt = 0; mt < 4; ++mt)
#pragma unroll
            for (int nt = 0; nt < 4; ++nt)
                acc[mt][nt] = __builtin_amdgcn_mfma_f32_16x16x32_bf16(
                    af[mt], bfr[nt], acc[mt][nt], 0, 0, 0);
    }

    // C/D layout: row=(lane>>4)*4+reg, col=lane&15 (m89/m91-verified)
#pragma unroll
    for (int mt = 0; mt < 4; ++mt) {
#pragma unroll
        for (int nt = 0; nt < 4; ++nt) {
#pragma unroll
            for (int r = 0; r < 4; ++r) {
                int rowl = wm * 64 + mt * 16 + q * 4 + r;
                int col = wn * 64 + nt * 16 + lm;
                int gm = m0 + rowl, gn = n0 + col;
                float x = acc[mt][nt][r];
                if (EPI == EP_GELU)
                    x = 0.5f * x * (1.0f + erff(x * 0.70710678118f));
                if (EPI == EP_VT) {
                    // vwT[(b*64+win)*128 + ch][tok]
                    int wix = gm >> 8, tok = gm & 255;
                    ((u16*)Cv)[((size_t)wix * 128 + gn) * 256 + tok] = f2b(x);
                } else if (EPI == EP_STOREF) {
                    ((float*)Cv)[(size_t)gm * N + gn] = x;
                } else {
                    ((u16*)Cv)[(size_t)gm * N + gn] = f2b(x);
                }
            }
        }
    }
}

// ---------------------------------------------------------------------------
// Windowed attention, LDS = P only (33 KB). K/V fragments straight from
// global (L2-resident). One block = 64 Q rows of one window; grid = 2*64*4.
// ---------------------------------------------------------------------------
__global__ __launch_bounds__(256)
void attn_k(const u16* __restrict__ qw, const u16* __restrict__ kw,
            const u16* __restrict__ vt, u16* __restrict__ om)
{
    __shared__ __align__(16) u16 Ps[64 * 264];

    const int tid = threadIdx.x, w = tid >> 6, lane = tid & 63;
    const int lm = lane & 15, q = lane >> 4;
    const int bid = blockIdx.x;
    const int qc = bid & 3, win = (bid >> 2) & 63, b = bid >> 8;
    const int wi = win >> 3, wj = win & 7;
    const int q0 = qc * 64;
    const size_t wbase = (size_t)(b * 64 + win);
    const u16* kwb = kw + wbase * 256 * 128;
    const u16* qwb = qw + wbase * 256 * 128;
    const u16* vtb = vt + wbase * 128 * 256;

    // Q A-frags: A[m=lane&15][k=q*8+j]
    bf16x8 af[4];
    const u16* qrow = qwb + (size_t)(q0 + w * 16 + lm) * 128;
#pragma unroll
    for (int kt = 0; kt < 4; ++kt)
        af[kt] = *(const bf16x8*)(qrow + kt * 32 + q * 8);

    // S = Q K^T : B-frag element j = K[tok=nt*16+lm][k=kt*32+q*8+j]
    f32x4 s[16];
#pragma unroll
    for (int nt = 0; nt < 16; ++nt) { f32x4 z = {0.f, 0.f, 0.f, 0.f}; s[nt] = z; }
#pragma unroll
    for (int kt = 0; kt < 4; ++kt)
#pragma unroll
        for (int nt = 0; nt < 16; ++nt) {
            bf16x8 bf = *(const bf16x8*)(kwb + (size_t)(nt * 16 + lm) * 128 + kt * 32 + q * 8);
            s[nt] = __builtin_amdgcn_mfma_f32_16x16x32_bf16(af[kt], bf, s[nt], 0, 0, 0);
        }

    // analytic Swin mask (regions [0,112)/[112,120)/[120,128) on shifted grid)
    int idk[16];
#pragma unroll
    for (int nt = 0; nt < 16; ++nt) {
        int rh = (wi == 7) ? ((nt >= 8) ? 2 : 1) : 0;   // key i = nt
        int rw = (wj == 7) ? ((lm >= 8) ? 2 : 1) : 0;   // key j = lm
        idk[nt] = rh * 3 + rw;
    }
    const float scale = 0.08838834764831845f;  // 1/sqrt(128)
#pragma unroll
    for (int r = 0; r < 4; ++r) {
        int tq = q0 + w * 16 + q * 4 + r;
        int iq = tq >> 4, jq = tq & 15;
        int rhq = (wi == 7) ? ((iq >= 8) ? 2 : 1) : 0;
        int rwq = (wj == 7) ? ((jq >= 8) ? 2 : 1) : 0;
        int idq = rhq * 3 + rwq;
        float sv[16];
        float mx = -1e30f;
#pragma unroll
        for (int nt = 0; nt < 16; ++nt) {
            float x = s[nt][r] * scale + ((idq != idk[nt]) ? -100.f : 0.f);
            sv[nt] = x; mx = fmaxf(mx, x);
        }
        mx = fmaxf(mx, __shfl_xor(mx, 1));
        mx = fmaxf(mx, __shfl_xor(mx, 2));
        mx = fmaxf(mx, __shfl_xor(mx, 4));
        mx = fmaxf(mx, __shfl_xor(mx, 8));
        float sum = 0.f;
#pragma unroll
        for (int nt = 0; nt < 16; ++nt) { float e = __expf(sv[nt] - mx); sv[nt] = e; sum += e; }
        sum += __shfl_xor(sum, 1);
        sum += __shfl_xor(sum, 2);
        sum += __shfl_xor(sum, 4);
        sum += __shfl_xor(sum, 8);
        float inv = 1.0f / sum;
#pragma unroll
        for (int nt = 0; nt < 16; ++nt)
            Ps[(w * 16 + q * 4 + r) * 264 + nt * 16 + lm] = f2b(sv[nt] * inv);
    }
    __syncthreads();

    // O = P V : P A-frags from LDS; V B-frag j = V[t=tt*32+q*8+j][ch=nt*16+lm]
    f32x4 o[8];
#pragma unroll
    for (int nt = 0; nt < 8; ++nt) { f32x4 z = {0.f, 0.f, 0.f, 0.f}; o[nt] = z; }
#pragma unroll
    for (int tt = 0; tt < 8; ++tt) {
        bf16x8 pf = *(const bf16x8*)(Ps + (w * 16 + lm) * 264 + tt * 32 + q * 8);
#pragma unroll
        for (int nt = 0; nt < 8; ++nt) {
            bf16x8 vf = *(const bf16x8*)(vtb + (size_t)(nt * 16 + lm) * 256 + tt * 32 + q * 8);
            o[nt] = __builtin_amdgcn_mfma_f32_16x16x32_bf16(pf, vf, o[nt], 0, 0, 0);
        }
    }
    // scatter back to source-order rows (undo shift+partition), bf16
#pragma unroll
    for (int r = 0; r < 4; ++r) {
        int t = q0 + w * 16 + q * 4 + r;
        int i = t >> 4, j = t & 15;
        int h = (wi * 16 + i + 8) & 127;
        int w2 = (wj * 16 + j + 8) & 127;
        size_t orow = ((size_t)b * 16384 + h * 128 + w2) * 128;
#pragma unroll
        for (int nt = 0; nt < 8; ++nt)
            om[orow + nt * 16 + lm] = f2b(o[nt][r]);
    }
}

// ---------------------------------------------------------------------------
// LayerNorm over C=128, fp32 input, optional fp32 residual add.
// OUT_BF: write bf16 (for concat path) else fp32. 2 threads per row.
// ---------------------------------------------------------------------------
template <bool OUT_BF>
__global__ __launch_bounds__(256)
void ln_f(const float* __restrict__ X, const float* __restrict__ g,
          const float* __restrict__ bb, const float* __restrict__ add,
          void* __restrict__ outv)
{
    int tid = threadIdx.x;
    int row = blockIdx.x * 128 + (tid >> 1);
    int half = tid & 1;
    const float* xr = X + (size_t)row * 128 + half * 64;
    float v[64];
    float s = 0.f, s2 = 0.f;
#pragma unroll
    for (int i = 0; i < 16; ++i) {
        f32x4 t = *(const f32x4*)(xr + i * 4);
#pragma unroll
        for (int j = 0; j < 4; ++j) {
            float f = t[j]; v[i * 4 + j] = f; s += f; s2 += f * f;
        }
    }
    s  += __shfl_xor(s, 1);
    s2 += __shfl_xor(s2, 1);
    float mean = s * (1.f / 128.f);
    float var = s2 * (1.f / 128.f) - mean * mean;
    var = fmaxf(var, 0.f);
    float rs = rsqrtf(var + 1e-5f);
    const float* ar = add ? (add + (size_t)row * 128 + half * 64) : nullptr;
#pragma unroll
    for (int i = 0; i < 64; ++i) {
        int c = half * 64 + i;
        float y = (v[i] - mean) * rs * g[c] + bb[c];
        if (add) y += ar[i];
        if (OUT_BF) ((u16*)outv)[(size_t)row * 128 + c] = f2b(y);
        else        ((float*)outv)[(size_t)row * 128 + c] = y;
    }
}

// ---------------------------------------------------------------------------
// Prep: transpose + fp32->bf16 weights; fp32->bf16 activations.
// ---------------------------------------------------------------------------
__global__ void prep_w(const float* __restrict__ Wq, const float* __restrict__ Wk,
                       const float* __restrict__ Wv, const float* __restrict__ Wm,
                       const float* __restrict__ W1, const float* __restrict__ W2,
                       u16* __restrict__ ws)
{
    int idx = blockIdx.x * 256 + threadIdx.x;
    if (idx < 65536) {                       // Wq,Wk,Wv,Wm: 128x128
        int m = idx >> 14, e = idx & 16383;
        const float* src = (m == 0) ? Wq : (m == 1) ? Wk : (m == 2) ? Wv : Wm;
        int k = e >> 7, n = e & 127;
        ws[m * 16384 + n * 128 + k] = f2b(src[e]);
    } else if (idx < 65536 + 262144) {       // W1: (256,1024) -> (1024,256)
        int e = idx - 65536;
        int k = e >> 10, n = e & 1023;
        ws[65536 + n * 256 + k] = f2b(W1[e]);
    } else {                                  // W2: (1024,128) -> (128,1024)
        int e = idx - (65536 + 262144);
        int k = e >> 7, n = e & 127;
        ws[327680 + n * 1024 + k] = f2b(W2[e]);
    }
}

__global__ void prep_x(const float* __restrict__ src, const float* __restrict__ tgt,
                       u16* __restrict__ srcb, u16* __restrict__ tgtb)
{
    int idx = blockIdx.x * 256 + threadIdx.x;   // 0..2097151
    const float* s; u16* d; int i;
    if (idx < 1048576) { s = src; d = srcb; i = idx * 4; }
    else               { s = tgt; d = tgtb; i = (idx - 1048576) * 4; }
    f32x4 v = *(const f32x4*)(s + i);
    u16x4 o; o[0] = f2b(v[0]); o[1] = f2b(v[1]); o[2] = f2b(v[2]); o[3] = f2b(v[3]);
    *(u16x4*)(d + i) = o;
}

// ---------------------------------------------------------------------------
// Workspace layout (u16 element offsets); total 59,179,008 u16 = ~113 MB.
// ---------------------------------------------------------------------------
#define OFF_WQT  0u
#define OFF_WKT  16384u
#define OFF_WVT  32768u
#define OFF_WMT  49152u
#define OFF_W1T  65536u
#define OFF_W2T  327680u
#define OFF_SRCB 458752u
#define OFF_TGTB 4653056u
#define OFF_QW   8847360u
#define OFF_KW   13041664u
#define OFF_VWT  17235968u
#define OFF_ATTN 21430272u
#define OFF_HID  25624576u     // bf16 32768x1024, ends 59179008
// overlays (regions free by then):
#define OFF_MSGF 8847360u      // fp32 32768x128 over QW+KW (after attn)
#define OFF_MSGB 17235968u     // bf16 over VWT (after attn)
#define OFF_F2   17235968u     // fp32 32768x128 over VWT+ATTN (after FFN1;
                               // clobbers MSGB which is dead by then)

extern "C" void kernel_launch(void* const* d_in, const int* in_sizes, int n_in,
                              void* d_out, int out_size, void* d_ws, size_t ws_size,
                              hipStream_t stream)
{
    (void)in_sizes; (void)n_in; (void)out_size; (void)ws_size;
    const float* source = (const float*)d_in[0];
    const float* target = (const float*)d_in[1];
    const float* Wq = (const float*)d_in[2];
    const float* Wk = (const float*)d_in[3];
    const float* Wv = (const float*)d_in[4];
    const float* Wm = (const float*)d_in[5];
    const float* g1 = (const float*)d_in[6];
    const float* b1 = (const float*)d_in[7];
    const float* W1 = (const float*)d_in[8];
    const float* W2 = (const float*)d_in[9];
    const float* g2 = (const float*)d_in[10];
    const float* b2 = (const float*)d_in[11];
    u16* ws = (u16*)d_ws;
    float* out = (float*)d_out;

    prep_w<<<1792, 256, 0, stream>>>(Wq, Wk, Wv, Wm, W1, W2, ws);
    prep_x<<<8192, 256, 0, stream>>>(source, target, ws + OFF_SRCB, ws + OFF_TGTB);
    // q/k/v projections into window layout; v stored transposed per window
    gemm_mfma<AM_WIN, EP_STORE><<<dim3(256, 1), 256, 0, stream>>>(
        ws + OFF_SRCB, nullptr, ws + OFF_WQT, ws + OFF_QW, 128, 128);
    gemm_mfma<AM_WIN, EP_STORE><<<dim3(256, 1), 256, 0, stream>>>(
        ws + OFF_TGTB, nullptr, ws + OFF_WKT, ws + OFF_KW, 128, 128);
    gemm_mfma<AM_WIN, EP_VT><<<dim3(256, 1), 256, 0, stream>>>(
        ws + OFF_TGTB, nullptr, ws + OFF_WVT, ws + OFF_VWT, 128, 128);
    // windowed attention -> source-order rows (bf16)
    attn_k<<<512, 256, 0, stream>>>(ws + OFF_QW, ws + OFF_KW, ws + OFF_VWT, ws + OFF_ATTN);
    // message = LN(attn @ Wm)
    gemm_mfma<AM_PLAIN, EP_STOREF><<<dim3(256, 1), 256, 0, stream>>>(
        ws + OFF_ATTN, nullptr, ws + OFF_WMT, (void*)(ws + OFF_MSGF), 128, 128);
    ln_f<true><<<256, 256, 0, stream>>>(
        (const float*)(ws + OFF_MSGF), g1, b1, nullptr, ws + OFF_MSGB);
    // ffn: gelu(concat(src,msg) @ W1) @ W2 -> LN -> + source
    gemm_mfma<AM_CAT, EP_GELU><<<dim3(256, 8), 256, 0, stream>>>(
        ws + OFF_SRCB, ws + OFF_MSGB, ws + OFF_W1T, ws + OFF_HID, 256, 1024);
    gemm_mfma<AM_PLAIN, EP_STOREF><<<dim3(256, 1), 256, 0, stream>>>(
        ws + OFF_HID, nullptr, ws + OFF_W2T, (void*)(ws + OFF_F2), 1024, 128);
    ln_f<false><<<256, 256, 0, stream>>>(
        (const float*)(ws + OFF_F2), g2, b2, source, out);
}

// Round 3
// 273.742 us; speedup vs baseline: 1.2960x; 1.2960x over previous
//
#include <hip/hip_runtime.h>
#include <math.h>
#include <stdint.h>

// ---------------------------------------------------------------------------
// TransformerLayer (Swin-style) on MI355X. FP32 I/O; bf16 MFMA internals.
// B=2, H=W=128, C=128, NS=8 -> 64 windows x 256 tokens; HID=1024.
// R3: coalesced LayerNorm (32 lanes/row, float4) + LDS-staged vectorized
//     bf16 GEMM epilogues (fixes ~20x sector write amplification seen in R2:
//     ln_f WRITE_SIZE 320MB vs 16MB logical, 78us each).
// ---------------------------------------------------------------------------

typedef unsigned short u16;
typedef __attribute__((ext_vector_type(8))) short bf16x8;   // 8 bf16 (4 VGPRs)
typedef __attribute__((ext_vector_type(4))) float f32x4;
typedef __attribute__((ext_vector_type(4))) short u16x4;

__device__ __forceinline__ u16 f2b(float f) {
    unsigned int i = __float_as_uint(f);
    unsigned int r = (i + 0x7fffu + ((i >> 16) & 1u)) >> 16;
    return (u16)r;
}

// 16B async global->LDS copy (m97-verified). LDS dest wave-uniform + lane*16.
__device__ __forceinline__ void cp16(const void* g, void* l) {
    auto* gp = reinterpret_cast<const __attribute__((address_space(1))) unsigned int*>(
        reinterpret_cast<uintptr_t>(g));
    auto* lp = reinterpret_cast<__attribute__((address_space(3))) unsigned int*>(
        reinterpret_cast<uintptr_t>(l));
    __builtin_amdgcn_global_load_lds(gp, lp, 16, 0, 0);
}

// window row (b*16384 + win*256 + t) -> source-order row (b*16384 + h*128 + w)
__device__ __forceinline__ int win_map(int gm) {
    int b = gm >> 14, rr = gm & 16383;
    int win = rr >> 8, t = rr & 255;
    int wi = win >> 3, wj = win & 7, i = t >> 4, j = t & 15;
    int h = (wi * 16 + i + 8) & 127;
    int w = (wj * 16 + j + 8) & 127;
    return (b << 14) + h * 128 + w;
}

enum { AM_PLAIN = 0, AM_WIN = 1, AM_CAT = 2 };
enum { EP_STORE = 0, EP_VT = 1, EP_GELU = 2, EP_STOREF = 3 };

// ---------------------------------------------------------------------------
// MFMA GEMM: C[M x N] = A[M x K] * Bt[N x K]^T   (m97 structure)
// bf16 epilogues staged through LDS (Ts, stride 136 u16 -> 16B-aligned rows)
// so global stores are 16B/lane fully-coalesced dwordx4.
// ---------------------------------------------------------------------------
template <int AMODE, int EPI>
__global__ __launch_bounds__(256, 2)
void gemm_mfma(const u16* __restrict__ A0, const u16* __restrict__ A1,
               const u16* __restrict__ Bt, void* __restrict__ Cv,
               int K, int N)
{
    __shared__ __align__(16) u16 As[128 * 32];
    __shared__ __align__(16) u16 Bs[128 * 32];
    __shared__ __align__(16) u16 Ts[128 * 136];   // epilogue staging (bf16 paths)

    const int tid = threadIdx.x;
    const int w = tid >> 6, lane = tid & 63;
    const int lm = lane & 15, q = lane >> 4;
    const int wm = w >> 1, wn = w & 1;
    const int m0 = blockIdx.x * 128, n0 = blockIdx.y * 128;

    size_t aoff[2], boff[2];
#pragma unroll
    for (int i = 0; i < 2; ++i) {
        int row = w * 32 + i * 16 + (lane >> 2);
        int gm = m0 + row;
        if (AMODE == AM_WIN)      aoff[i] = (size_t)win_map(gm) * 128 + (lane & 3) * 8;
        else if (AMODE == AM_CAT) aoff[i] = (size_t)gm * 128 + (lane & 3) * 8;
        else                      aoff[i] = (size_t)gm * K + (lane & 3) * 8;
        boff[i] = (size_t)(n0 + row) * K + (lane & 3) * 8;
    }

    f32x4 acc[4][4] = {};
    const int KT = K >> 5;
    for (int kt = 0; kt < KT; ++kt) {
        __syncthreads();
#pragma unroll
        for (int i = 0; i < 2; ++i) {
            const u16* ga;
            if (AMODE == AM_CAT) {
                int kk = kt * 32 + (lane & 3) * 8;
                ga = (kk < 128) ? (A0 + aoff[i] + kt * 32)
                                : (A1 + aoff[i] + kt * 32 - 128);
            } else {
                ga = A0 + aoff[i] + kt * 32;
            }
            cp16(ga, (void*)(As + (w * 32 + i * 16) * 32));
            cp16(Bt + boff[i] + kt * 32, (void*)(Bs + (w * 32 + i * 16) * 32));
        }
        __syncthreads();
        bf16x8 af[4], bfr[4];
#pragma unroll
        for (int t = 0; t < 4; ++t)
            af[t] = *(const bf16x8*)(As + (wm * 64 + t * 16 + lm) * 32 + q * 8);
#pragma unroll
        for (int t = 0; t < 4; ++t)
            bfr[t] = *(const bf16x8*)(Bs + (wn * 64 + t * 16 + lm) * 32 + q * 8);
#pragma unroll
        for (int mt = 0; mt < 4; ++mt)
#pragma unroll
            for (int nt = 0; nt < 4; ++nt)
                acc[mt][nt] = __builtin_amdgcn_mfma_f32_16x16x32_bf16(
                    af[mt], bfr[nt], acc[mt][nt], 0, 0, 0);
    }

    // C/D layout: row=(lane>>4)*4+reg, col=lane&15 (m89/m91-verified)
    if (EPI == EP_STOREF) {
        // fp32 scalar stores: 16 lanes x 4B = full 64B sectors, no amplification
#pragma unroll
        for (int mt = 0; mt < 4; ++mt)
#pragma unroll
            for (int nt = 0; nt < 4; ++nt)
#pragma unroll
                for (int r = 0; r < 4; ++r) {
                    int rowl = wm * 64 + mt * 16 + q * 4 + r;
                    int col = wn * 64 + nt * 16 + lm;
                    ((float*)Cv)[(size_t)(m0 + rowl) * N + n0 + col] = acc[mt][nt][r];
                }
    } else {
        // stage bf16 tile in LDS (transposed for EP_VT), then 16B/lane stores
#pragma unroll
        for (int mt = 0; mt < 4; ++mt)
#pragma unroll
            for (int nt = 0; nt < 4; ++nt)
#pragma unroll
                for (int r = 0; r < 4; ++r) {
                    int rowl = wm * 64 + mt * 16 + q * 4 + r;
                    int col = wn * 64 + nt * 16 + lm;
                    float x = acc[mt][nt][r];
                    if (EPI == EP_GELU)
                        x = 0.5f * x * (1.0f + erff(x * 0.70710678118f));
                    int idx = (EPI == EP_VT) ? col * 136 + rowl : rowl * 136 + col;
                    Ts[idx] = f2b(x);
                }
        __syncthreads();
        const int c8 = (tid & 15) * 8;
#pragma unroll
        for (int i = 0; i < 8; ++i) {
            int rr = i * 16 + (tid >> 4);
            bf16x8 t = *(const bf16x8*)(Ts + rr * 136 + c8);
            if (EPI == EP_VT) {
                // vwT[(b*64+win)*128 + ch][tok]; block covers one window half
                int wix = m0 >> 8, tok0 = m0 & 255;
                *(bf16x8*)((u16*)Cv + (size_t)wix * 32768 + (size_t)rr * 256 + tok0 + c8) = t;
            } else {
                *(bf16x8*)((u16*)Cv + (size_t)(m0 + rr) * N + n0 + c8) = t;
            }
        }
    }
}

// ---------------------------------------------------------------------------
// Windowed attention, LDS = P only (33 KB). K/V fragments from global (L2).
// One block = 64 Q rows of one window; grid = 2*64*4.
// ---------------------------------------------------------------------------
__global__ __launch_bounds__(256)
void attn_k(const u16* __restrict__ qw, const u16* __restrict__ kw,
            const u16* __restrict__ vt, u16* __restrict__ om)
{
    __shared__ __align__(16) u16 Ps[64 * 264];

    const int tid = threadIdx.x, w = tid >> 6, lane = tid & 63;
    const int lm = lane & 15, q = lane >> 4;
    const int bid = blockIdx.x;
    const int qc = bid & 3, win = (bid >> 2) & 63, b = bid >> 8;
    const int wi = win >> 3, wj = win & 7;
    const int q0 = qc * 64;
    const size_t wbase = (size_t)(b * 64 + win);
    const u16* kwb = kw + wbase * 256 * 128;
    const u16* qwb = qw + wbase * 256 * 128;
    const u16* vtb = vt + wbase * 128 * 256;

    // Q A-frags: A[m=lane&15][k=q*8+j]
    bf16x8 af[4];
    const u16* qrow = qwb + (size_t)(q0 + w * 16 + lm) * 128;
#pragma unroll
    for (int kt = 0; kt < 4; ++kt)
        af[kt] = *(const bf16x8*)(qrow + kt * 32 + q * 8);

    // S = Q K^T : B-frag element j = K[tok=nt*16+lm][k=kt*32+q*8+j]
    f32x4 s[16];
#pragma unroll
    for (int nt = 0; nt < 16; ++nt) { f32x4 z = {0.f, 0.f, 0.f, 0.f}; s[nt] = z; }
#pragma unroll
    for (int kt = 0; kt < 4; ++kt)
#pragma unroll
        for (int nt = 0; nt < 16; ++nt) {
            bf16x8 bf = *(const bf16x8*)(kwb + (size_t)(nt * 16 + lm) * 128 + kt * 32 + q * 8);
            s[nt] = __builtin_amdgcn_mfma_f32_16x16x32_bf16(af[kt], bf, s[nt], 0, 0, 0);
        }

    // analytic Swin mask (regions [0,112)/[112,120)/[120,128) on shifted grid)
    int idk[16];
#pragma unroll
    for (int nt = 0; nt < 16; ++nt) {
        int rh = (wi == 7) ? ((nt >= 8) ? 2 : 1) : 0;   // key i = nt
        int rw = (wj == 7) ? ((lm >= 8) ? 2 : 1) : 0;   // key j = lm
        idk[nt] = rh * 3 + rw;
    }
    const float scale = 0.08838834764831845f;  // 1/sqrt(128)
#pragma unroll
    for (int r = 0; r < 4; ++r) {
        int tq = q0 + w * 16 + q * 4 + r;
        int iq = tq >> 4, jq = tq & 15;
        int rhq = (wi == 7) ? ((iq >= 8) ? 2 : 1) : 0;
        int rwq = (wj == 7) ? ((jq >= 8) ? 2 : 1) : 0;
        int idq = rhq * 3 + rwq;
        float sv[16];
        float mx = -1e30f;
#pragma unroll
        for (int nt = 0; nt < 16; ++nt) {
            float x = s[nt][r] * scale + ((idq != idk[nt]) ? -100.f : 0.f);
            sv[nt] = x; mx = fmaxf(mx, x);
        }
        mx = fmaxf(mx, __shfl_xor(mx, 1));
        mx = fmaxf(mx, __shfl_xor(mx, 2));
        mx = fmaxf(mx, __shfl_xor(mx, 4));
        mx = fmaxf(mx, __shfl_xor(mx, 8));
        float sum = 0.f;
#pragma unroll
        for (int nt = 0; nt < 16; ++nt) { float e = __expf(sv[nt] - mx); sv[nt] = e; sum += e; }
        sum += __shfl_xor(sum, 1);
        sum += __shfl_xor(sum, 2);
        sum += __shfl_xor(sum, 4);
        sum += __shfl_xor(sum, 8);
        float inv = 1.0f / sum;
#pragma unroll
        for (int nt = 0; nt < 16; ++nt)
            Ps[(w * 16 + q * 4 + r) * 264 + nt * 16 + lm] = f2b(sv[nt] * inv);
    }
    __syncthreads();

    // O = P V : P A-frags from LDS; V B-frag j = V[t=tt*32+q*8+j][ch=nt*16+lm]
    f32x4 o[8];
#pragma unroll
    for (int nt = 0; nt < 8; ++nt) { f32x4 z = {0.f, 0.f, 0.f, 0.f}; o[nt] = z; }
#pragma unroll
    for (int tt = 0; tt < 8; ++tt) {
        bf16x8 pf = *(const bf16x8*)(Ps + (w * 16 + lm) * 264 + tt * 32 + q * 8);
#pragma unroll
        for (int nt = 0; nt < 8; ++nt) {
            bf16x8 vf = *(const bf16x8*)(vtb + (size_t)(nt * 16 + lm) * 256 + tt * 32 + q * 8);
            o[nt] = __builtin_amdgcn_mfma_f32_16x16x32_bf16(pf, vf, o[nt], 0, 0, 0);
        }
    }
    // scatter back to source-order rows (undo shift+partition), bf16
#pragma unroll
    for (int r = 0; r < 4; ++r) {
        int t = q0 + w * 16 + q * 4 + r;
        int i = t >> 4, j = t & 15;
        int h = (wi * 16 + i + 8) & 127;
        int w2 = (wj * 16 + j + 8) & 127;
        size_t orow = ((size_t)b * 16384 + h * 128 + w2) * 128;
#pragma unroll
        for (int nt = 0; nt < 8; ++nt)
            om[orow + nt * 16 + lm] = f2b(o[nt][r]);
    }
}

// ---------------------------------------------------------------------------
// LayerNorm over C=128, fp32 input, optional fp32 residual add.
// 32 lanes per row, float4 loads/stores -> fully coalesced (512B/instr).
// OUT_BF: write bf16 (concat path) else fp32.
// ---------------------------------------------------------------------------
template <bool OUT_BF>
__global__ __launch_bounds__(256)
void ln_f(const float* __restrict__ X, const float* __restrict__ g,
          const float* __restrict__ bb, const float* __restrict__ add,
          void* __restrict__ outv)
{
    const int l32 = threadIdx.x & 31;
    const int row = blockIdx.x * 8 + (threadIdx.x >> 5);
    const size_t base = (size_t)row * 128 + l32 * 4;
    f32x4 v = *(const f32x4*)(X + base);
    float s = v[0] + v[1] + v[2] + v[3];
    float s2 = v[0] * v[0] + v[1] * v[1] + v[2] * v[2] + v[3] * v[3];
#pragma unroll
    for (int m = 1; m < 32; m <<= 1) {
        s  += __shfl_xor(s, m);
        s2 += __shfl_xor(s2, m);
    }
    float mean = s * (1.f / 128.f);
    float var = fmaxf(s2 * (1.f / 128.f) - mean * mean, 0.f);
    float rs = rsqrtf(var + 1e-5f);
    f32x4 gg = *(const f32x4*)(g + l32 * 4);
    f32x4 bv = *(const f32x4*)(bb + l32 * 4);
    f32x4 y;
#pragma unroll
    for (int j = 0; j < 4; ++j) y[j] = (v[j] - mean) * rs * gg[j] + bv[j];
    if (add) {
        f32x4 av = *(const f32x4*)(add + base);
#pragma unroll
        for (int j = 0; j < 4; ++j) y[j] += av[j];
    }
    if (OUT_BF) {
        u16x4 o; o[0] = f2b(y[0]); o[1] = f2b(y[1]); o[2] = f2b(y[2]); o[3] = f2b(y[3]);
        *(u16x4*)((u16*)outv + base) = o;
    } else {
        *(f32x4*)((float*)outv + base) = y;
    }
}

// ---------------------------------------------------------------------------
// Prep: transpose + fp32->bf16 weights; fp32->bf16 activations.
// ---------------------------------------------------------------------------
__global__ void prep_w(const float* __restrict__ Wq, const float* __restrict__ Wk,
                       const float* __restrict__ Wv, const float* __restrict__ Wm,
                       const float* __restrict__ W1, const float* __restrict__ W2,
                       u16* __restrict__ ws)
{
    int idx = blockIdx.x * 256 + threadIdx.x;
    if (idx < 65536) {                       // Wq,Wk,Wv,Wm: 128x128
        int m = idx >> 14, e = idx & 16383;
        const float* src = (m == 0) ? Wq : (m == 1) ? Wk : (m == 2) ? Wv : Wm;
        int k = e >> 7, n = e & 127;
        ws[m * 16384 + n * 128 + k] = f2b(src[e]);
    } else if (idx < 65536 + 262144) {       // W1: (256,1024) -> (1024,256)
        int e = idx - 65536;
        int k = e >> 10, n = e & 1023;
        ws[65536 + n * 256 + k] = f2b(W1[e]);
    } else {                                  // W2: (1024,128) -> (128,1024)
        int e = idx - (65536 + 262144);
        int k = e >> 7, n = e & 127;
        ws[327680 + n * 1024 + k] = f2b(W2[e]);
    }
}

__global__ void prep_x(const float* __restrict__ src, const float* __restrict__ tgt,
                       u16* __restrict__ srcb, u16* __restrict__ tgtb)
{
    int idx = blockIdx.x * 256 + threadIdx.x;   // 0..2097151
    const float* s; u16* d; int i;
    if (idx < 1048576) { s = src; d = srcb; i = idx * 4; }
    else               { s = tgt; d = tgtb; i = (idx - 1048576) * 4; }
    f32x4 v = *(const f32x4*)(s + i);
    u16x4 o; o[0] = f2b(v[0]); o[1] = f2b(v[1]); o[2] = f2b(v[2]); o[3] = f2b(v[3]);
    *(u16x4*)(d + i) = o;
}

// ---------------------------------------------------------------------------
// Workspace layout (u16 element offsets); total 59,179,008 u16 = ~113 MB.
// ---------------------------------------------------------------------------
#define OFF_WQT  0u
#define OFF_WKT  16384u
#define OFF_WVT  32768u
#define OFF_WMT  49152u
#define OFF_W1T  65536u
#define OFF_W2T  327680u
#define OFF_SRCB 458752u
#define OFF_TGTB 4653056u
#define OFF_QW   8847360u
#define OFF_KW   13041664u
#define OFF_VWT  17235968u
#define OFF_ATTN 21430272u
#define OFF_HID  25624576u     // bf16 32768x1024, ends 59179008
// overlays (regions free by then):
#define OFF_MSGF 8847360u      // fp32 32768x128 over QW+KW (after attn)
#define OFF_MSGB 17235968u     // bf16 over VWT (after attn)
#define OFF_F2   17235968u     // fp32 32768x128 over VWT+ATTN (after FFN1)

extern "C" void kernel_launch(void* const* d_in, const int* in_sizes, int n_in,
                              void* d_out, int out_size, void* d_ws, size_t ws_size,
                              hipStream_t stream)
{
    (void)in_sizes; (void)n_in; (void)out_size; (void)ws_size;
    const float* source = (const float*)d_in[0];
    const float* target = (const float*)d_in[1];
    const float* Wq = (const float*)d_in[2];
    const float* Wk = (const float*)d_in[3];
    const float* Wv = (const float*)d_in[4];
    const float* Wm = (const float*)d_in[5];
    const float* g1 = (const float*)d_in[6];
    const float* b1 = (const float*)d_in[7];
    const float* W1 = (const float*)d_in[8];
    const float* W2 = (const float*)d_in[9];
    const float* g2 = (const float*)d_in[10];
    const float* b2 = (const float*)d_in[11];
    u16* ws = (u16*)d_ws;
    float* out = (float*)d_out;

    prep_w<<<1792, 256, 0, stream>>>(Wq, Wk, Wv, Wm, W1, W2, ws);
    prep_x<<<8192, 256, 0, stream>>>(source, target, ws + OFF_SRCB, ws + OFF_TGTB);
    // q/k/v projections into window layout; v stored transposed per window
    gemm_mfma<AM_WIN, EP_STORE><<<dim3(256, 1), 256, 0, stream>>>(
        ws + OFF_SRCB, nullptr, ws + OFF_WQT, ws + OFF_QW, 128, 128);
    gemm_mfma<AM_WIN, EP_STORE><<<dim3(256, 1), 256, 0, stream>>>(
        ws + OFF_TGTB, nullptr, ws + OFF_WKT, ws + OFF_KW, 128, 128);
    gemm_mfma<AM_WIN, EP_VT><<<dim3(256, 1), 256, 0, stream>>>(
        ws + OFF_TGTB, nullptr, ws + OFF_WVT, ws + OFF_VWT, 128, 128);
    // windowed attention -> source-order rows (bf16)
    attn_k<<<512, 256, 0, stream>>>(ws + OFF_QW, ws + OFF_KW, ws + OFF_VWT, ws + OFF_ATTN);
    // message = LN(attn @ Wm)
    gemm_mfma<AM_PLAIN, EP_STOREF><<<dim3(256, 1), 256, 0, stream>>>(
        ws + OFF_ATTN, nullptr, ws + OFF_WMT, (void*)(ws + OFF_MSGF), 128, 128);
    ln_f<true><<<4096, 256, 0, stream>>>(
        (const float*)(ws + OFF_MSGF), g1, b1, nullptr, ws + OFF_MSGB);
    // ffn: gelu(concat(src,msg) @ W1) @ W2 -> LN -> + source
    gemm_mfma<AM_CAT, EP_GELU><<<dim3(256, 8), 256, 0, stream>>>(
        ws + OFF_SRCB, ws + OFF_MSGB, ws + OFF_W1T, ws + OFF_HID, 256, 1024);
    gemm_mfma<AM_PLAIN, EP_STOREF><<<dim3(256, 1), 256, 0, stream>>>(
        ws + OFF_HID, nullptr, ws + OFF_W2T, (void*)(ws + OFF_F2), 1024, 128);
    ln_f<false><<<4096, 256, 0, stream>>>(
        (const float*)(ws + OFF_F2), g2, b2, source, out);
}

// Round 4
// 233.827 us; speedup vs baseline: 1.5172x; 1.1707x over previous
//
#include <hip/hip_runtime.h>
#include <math.h>
#include <stdint.h>

// ---------------------------------------------------------------------------
// TransformerLayer (Swin-style) on MI355X. FP32 I/O; bf16 MFMA internals.
// B=2, H=W=128, C=128, NS=8 -> 64 windows x 256 tokens; HID=1024.
// R4: fast-erf gelu (A-S 7.1.26), LDS union (Ts over As/Bs), fused QKV
//     (one dispatch, grid 256x3), LN fused into the two N=128 GEMMs
//     (BM=64, fp32 LDS row stats) -- removes ln_f dispatches entirely.
// ---------------------------------------------------------------------------

typedef unsigned short u16;
typedef __attribute__((ext_vector_type(8))) short bf16x8;   // 8 bf16 (4 VGPRs)
typedef __attribute__((ext_vector_type(4))) float f32x4;
typedef __attribute__((ext_vector_type(4))) short u16x4;

__device__ __forceinline__ u16 f2b(float f) {
    unsigned int i = __float_as_uint(f);
    unsigned int r = (i + 0x7fffu + ((i >> 16) & 1u)) >> 16;
    return (u16)r;
}

// exact-gelu via Abramowitz-Stegun 7.1.26 erf (max err 1.5e-7), ~13 VALU
__device__ __forceinline__ float fast_gelu(float x) {
    float y = fabsf(x) * 0.70710678118f;
    float t = __builtin_amdgcn_rcpf(fmaf(0.3275911f, y, 1.0f));
    float p = fmaf(fmaf(fmaf(fmaf(1.061405429f, t, -1.453152027f), t,
                             1.421413741f), t, -0.284496736f), t, 0.254829592f) * t;
    float e = __expf(-y * y);
    float erf_abs = fmaf(-p, e, 1.0f);
    float s = copysignf(erf_abs, x);
    return 0.5f * x * (1.0f + s);
}

// 16B async global->LDS copy (m97-verified). LDS dest wave-uniform + lane*16.
__device__ __forceinline__ void cp16(const void* g, void* l) {
    auto* gp = reinterpret_cast<const __attribute__((address_space(1))) unsigned int*>(
        reinterpret_cast<uintptr_t>(g));
    auto* lp = reinterpret_cast<__attribute__((address_space(3))) unsigned int*>(
        reinterpret_cast<uintptr_t>(l));
    __builtin_amdgcn_global_load_lds(gp, lp, 16, 0, 0);
}

// window row (b*16384 + win*256 + t) -> source-order row (b*16384 + h*128 + w)
__device__ __forceinline__ int win_map(int gm) {
    int b = gm >> 14, rr = gm & 16383;
    int win = rr >> 8, t = rr & 255;
    int wi = win >> 3, wj = win & 7, i = t >> 4, j = t & 15;
    int h = (wi * 16 + i + 8) & 127;
    int w = (wj * 16 + j + 8) & 127;
    return (b << 14) + h * 128 + w;
}

// ---------------------------------------------------------------------------
// Fused QKV: one dispatch, grid (256, 3). y=0: q=src@Wq (window layout),
// y=1: k=tgt@Wk (window layout), y=2: v=tgt@Wv stored transposed per window.
// BM=128, BK=32, K=128. Bt = concat [WqT;WkT;WvT] (384 x 128).
// ---------------------------------------------------------------------------
__global__ __launch_bounds__(256, 3)
void gemm_qkv(const u16* __restrict__ srcb, const u16* __restrict__ tgtb,
              const u16* __restrict__ Bt, u16* __restrict__ qw,
              u16* __restrict__ kw, u16* __restrict__ vwt)
{
    __shared__ __align__(16) u16 SMEM[128 * 136];   // union: As|Bs then Ts
    u16* As = SMEM;            // 128x32
    u16* Bs = SMEM + 4096;     // 128x32
    u16* Ts = SMEM;            // 128x136 epilogue staging

    const int tid = threadIdx.x;
    const int w = tid >> 6, lane = tid & 63;
    const int lm = lane & 15, q = lane >> 4;
    const int wm = w >> 1, wn = w & 1;
    const int m0 = blockIdx.x * 128;
    const int y = blockIdx.y;
    const u16* Ab = (y == 0) ? srcb : tgtb;

    size_t aoff[2], boff[2];
#pragma unroll
    for (int i = 0; i < 2; ++i) {
        int row = w * 32 + i * 16 + (lane >> 2);
        aoff[i] = (size_t)win_map(m0 + row) * 128 + (lane & 3) * 8;
        boff[i] = (size_t)(y * 128 + row) * 128 + (lane & 3) * 8;
    }

    f32x4 acc[4][4] = {};
#pragma unroll
    for (int kt = 0; kt < 4; ++kt) {
        __syncthreads();
#pragma unroll
        for (int i = 0; i < 2; ++i) {
            cp16(Ab + aoff[i] + kt * 32, (void*)(As + (w * 32 + i * 16) * 32));
            cp16(Bt + boff[i] + kt * 32, (void*)(Bs + (w * 32 + i * 16) * 32));
        }
        __syncthreads();
        bf16x8 af[4], bfr[4];
#pragma unroll
        for (int t = 0; t < 4; ++t)
            af[t] = *(const bf16x8*)(As + (wm * 64 + t * 16 + lm) * 32 + q * 8);
#pragma unroll
        for (int t = 0; t < 4; ++t)
            bfr[t] = *(const bf16x8*)(Bs + (wn * 64 + t * 16 + lm) * 32 + q * 8);
#pragma unroll
        for (int mt = 0; mt < 4; ++mt)
#pragma unroll
            for (int nt = 0; nt < 4; ++nt)
                acc[mt][nt] = __builtin_amdgcn_mfma_f32_16x16x32_bf16(
                    af[mt], bfr[nt], acc[mt][nt], 0, 0, 0);
    }

    __syncthreads();   // protect As/Bs readers before Ts overlay writes
#pragma unroll
    for (int mt = 0; mt < 4; ++mt)
#pragma unroll
        for (int nt = 0; nt < 4; ++nt)
#pragma unroll
            for (int r = 0; r < 4; ++r) {
                int rowl = wm * 64 + mt * 16 + q * 4 + r;
                int col = wn * 64 + nt * 16 + lm;
                int idx = (y == 2) ? col * 136 + rowl : rowl * 136 + col;
                Ts[idx] = f2b(acc[mt][nt][r]);
            }
    __syncthreads();
    const int c8 = (tid & 15) * 8;
#pragma unroll
    for (int i = 0; i < 8; ++i) {
        int rr = i * 16 + (tid >> 4);
        bf16x8 t = *(const bf16x8*)(Ts + rr * 136 + c8);
        if (y == 2) {
            // vwT[(b*64+win)*128 + ch][tok]
            int wix = m0 >> 8, tok0 = m0 & 255;
            *(bf16x8*)(vwt + (size_t)wix * 32768 + (size_t)rr * 256 + tok0 + c8) = t;
        } else {
            u16* Cv = (y == 0) ? qw : kw;
            *(bf16x8*)(Cv + (size_t)(m0 + rr) * 128 + c8) = t;
        }
    }
}

// ---------------------------------------------------------------------------
// FFN1: gelu(concat(src,msg) @ W1) -> bf16 HID. BM=128, N=1024, K=256.
// grid (256, 8). Fast-erf gelu; LDS union.
// ---------------------------------------------------------------------------
__global__ __launch_bounds__(256, 3)
void gemm_ffn1(const u16* __restrict__ A0, const u16* __restrict__ A1,
               const u16* __restrict__ Bt, u16* __restrict__ C)
{
    __shared__ __align__(16) u16 SMEM[128 * 136];
    u16* As = SMEM;
    u16* Bs = SMEM + 4096;
    u16* Ts = SMEM;

    const int tid = threadIdx.x;
    const int w = tid >> 6, lane = tid & 63;
    const int lm = lane & 15, q = lane >> 4;
    const int wm = w >> 1, wn = w & 1;
    const int m0 = blockIdx.x * 128, n0 = blockIdx.y * 128;

    size_t aoff[2], boff[2];
#pragma unroll
    for (int i = 0; i < 2; ++i) {
        int row = w * 32 + i * 16 + (lane >> 2);
        aoff[i] = (size_t)(m0 + row) * 128 + (lane & 3) * 8;
        boff[i] = (size_t)(n0 + row) * 256 + (lane & 3) * 8;
    }

    f32x4 acc[4][4] = {};
#pragma unroll
    for (int kt = 0; kt < 8; ++kt) {
        __syncthreads();
#pragma unroll
        for (int i = 0; i < 2; ++i) {
            int kk = kt * 32 + (lane & 3) * 8;
            const u16* ga = (kk < 128) ? (A0 + aoff[i] + kt * 32)
                                       : (A1 + aoff[i] + kt * 32 - 128);
            cp16(ga, (void*)(As + (w * 32 + i * 16) * 32));
            cp16(Bt + boff[i] + kt * 32, (void*)(Bs + (w * 32 + i * 16) * 32));
        }
        __syncthreads();
        bf16x8 af[4], bfr[4];
#pragma unroll
        for (int t = 0; t < 4; ++t)
            af[t] = *(const bf16x8*)(As + (wm * 64 + t * 16 + lm) * 32 + q * 8);
#pragma unroll
        for (int t = 0; t < 4; ++t)
            bfr[t] = *(const bf16x8*)(Bs + (wn * 64 + t * 16 + lm) * 32 + q * 8);
#pragma unroll
        for (int mt = 0; mt < 4; ++mt)
#pragma unroll
            for (int nt = 0; nt < 4; ++nt)
                acc[mt][nt] = __builtin_amdgcn_mfma_f32_16x16x32_bf16(
                    af[mt], bfr[nt], acc[mt][nt], 0, 0, 0);
    }

    __syncthreads();
#pragma unroll
    for (int mt = 0; mt < 4; ++mt)
#pragma unroll
        for (int nt = 0; nt < 4; ++nt)
#pragma unroll
            for (int r = 0; r < 4; ++r) {
                int rowl = wm * 64 + mt * 16 + q * 4 + r;
                int col = wn * 64 + nt * 16 + lm;
                Ts[rowl * 136 + col] = f2b(fast_gelu(acc[mt][nt][r]));
            }
    __syncthreads();
    const int c8 = (tid & 15) * 8;
#pragma unroll
    for (int i = 0; i < 8; ++i) {
        int rr = i * 16 + (tid >> 4);
        bf16x8 t = *(const bf16x8*)(Ts + rr * 136 + c8);
        *(bf16x8*)(C + (size_t)(m0 + rr) * 1024 + n0 + c8) = t;
    }
}

// ---------------------------------------------------------------------------
// N=128 GEMM with fused LayerNorm: out_row = LN(A@Bt^T) [* +resid, fp32 out].
// BM=64 (grid M/64=512 -> 2 blocks/CU), BK=32. fp32 LDS tile for exact stats.
// RESID=false: bf16 out (msg path). RESID=true: fp32 out = resid + LN (final).
// ---------------------------------------------------------------------------
template <bool RESID>
__global__ __launch_bounds__(256, 2)
void gemm_ln(const u16* __restrict__ A, const u16* __restrict__ Bt,
             const float* __restrict__ g, const float* __restrict__ bb,
             const float* __restrict__ resid, void* __restrict__ outv, int K)
{
    __shared__ __align__(16) float Tf[64 * 132];    // union: As|Bs then fp32 tile
    u16* As = (u16*)Tf;            // 64x32
    u16* Bs = (u16*)Tf + 2048;     // 128x32

    const int tid = threadIdx.x;
    const int w = tid >> 6, lane = tid & 63;
    const int lm = lane & 15, q = lane >> 4;
    const int wm = w >> 1, wn = w & 1;
    const int m0 = blockIdx.x * 64;

    size_t aoff = (size_t)(m0 + w * 16 + (lane >> 2)) * K + (lane & 3) * 8;
    size_t boff[2];
#pragma unroll
    for (int i = 0; i < 2; ++i)
        boff[i] = (size_t)(w * 32 + i * 16 + (lane >> 2)) * K + (lane & 3) * 8;

    f32x4 acc[2][4] = {};
    const int KT = K >> 5;
    for (int kt = 0; kt < KT; ++kt) {
        __syncthreads();
        cp16(A + aoff + kt * 32, (void*)(As + (w * 16) * 32));
        cp16(Bt + boff[0] + kt * 32, (void*)(Bs + (w * 32) * 32));
        cp16(Bt + boff[1] + kt * 32, (void*)(Bs + (w * 32 + 16) * 32));
        __syncthreads();
        bf16x8 af[2], bfr[4];
#pragma unroll
        for (int t = 0; t < 2; ++t)
            af[t] = *(const bf16x8*)(As + (wm * 32 + t * 16 + lm) * 32 + q * 8);
#pragma unroll
        for (int t = 0; t < 4; ++t)
            bfr[t] = *(const bf16x8*)(Bs + (wn * 64 + t * 16 + lm) * 32 + q * 8);
#pragma unroll
        for (int mt = 0; mt < 2; ++mt)
#pragma unroll
            for (int nt = 0; nt < 4; ++nt)
                acc[mt][nt] = __builtin_amdgcn_mfma_f32_16x16x32_bf16(
                    af[mt], bfr[nt], acc[mt][nt], 0, 0, 0);
    }

    __syncthreads();
#pragma unroll
    for (int mt = 0; mt < 2; ++mt)
#pragma unroll
        for (int nt = 0; nt < 4; ++nt)
#pragma unroll
            for (int r = 0; r < 4; ++r) {
                int rowl = wm * 32 + mt * 16 + q * 4 + r;
                int col = wn * 64 + nt * 16 + lm;
                Tf[rowl * 132 + col] = acc[mt][nt][r];
            }
    __syncthreads();

    const int c = tid & 15;
#pragma unroll
    for (int i = 0; i < 4; ++i) {
        int rr = i * 16 + (tid >> 4);
        f32x4 v0 = *(const f32x4*)(Tf + rr * 132 + c * 8);
        f32x4 v1 = *(const f32x4*)(Tf + rr * 132 + c * 8 + 4);
        float s = v0[0] + v0[1] + v0[2] + v0[3] + v1[0] + v1[1] + v1[2] + v1[3];
        float s2 = v0[0]*v0[0] + v0[1]*v0[1] + v0[2]*v0[2] + v0[3]*v0[3]
                 + v1[0]*v1[0] + v1[1]*v1[1] + v1[2]*v1[2] + v1[3]*v1[3];
#pragma unroll
        for (int m = 1; m < 16; m <<= 1) {
            s  += __shfl_xor(s, m);
            s2 += __shfl_xor(s2, m);
        }
        float mean = s * (1.f / 128.f);
        float var = fmaxf(s2 * (1.f / 128.f) - mean * mean, 0.f);
        float rs = rsqrtf(var + 1e-5f);
        f32x4 g0 = *(const f32x4*)(g + c * 8), g1 = *(const f32x4*)(g + c * 8 + 4);
        f32x4 b0 = *(const f32x4*)(bb + c * 8), b1 = *(const f32x4*)(bb + c * 8 + 4);
        f32x4 y0, y1;
#pragma unroll
        for (int j = 0; j < 4; ++j) {
            y0[j] = (v0[j] - mean) * rs * g0[j] + b0[j];
            y1[j] = (v1[j] - mean) * rs * g1[j] + b1[j];
        }
        size_t base = (size_t)(m0 + rr) * 128 + c * 8;
        if (RESID) {
            f32x4 a0 = *(const f32x4*)(resid + base);
            f32x4 a1 = *(const f32x4*)(resid + base + 4);
#pragma unroll
            for (int j = 0; j < 4; ++j) { y0[j] += a0[j]; y1[j] += a1[j]; }
            *(f32x4*)((float*)outv + base) = y0;
            *(f32x4*)((float*)outv + base + 4) = y1;
        } else {
            bf16x8 o;
#pragma unroll
            for (int j = 0; j < 4; ++j) { o[j] = f2b(y0[j]); o[j + 4] = f2b(y1[j]); }
            *(bf16x8*)((u16*)outv + base) = o;
        }
    }
}

// ---------------------------------------------------------------------------
// Windowed attention, LDS = P only (33 KB). K/V fragments from global (L2).
// One block = 64 Q rows of one window; grid = 2*64*4.
// ---------------------------------------------------------------------------
__global__ __launch_bounds__(256)
void attn_k(const u16* __restrict__ qw, const u16* __restrict__ kw,
            const u16* __restrict__ vt, u16* __restrict__ om)
{
    __shared__ __align__(16) u16 Ps[64 * 264];

    const int tid = threadIdx.x, w = tid >> 6, lane = tid & 63;
    const int lm = lane & 15, q = lane >> 4;
    const int bid = blockIdx.x;
    const int qc = bid & 3, win = (bid >> 2) & 63, b = bid >> 8;
    const int wi = win >> 3, wj = win & 7;
    const int q0 = qc * 64;
    const size_t wbase = (size_t)(b * 64 + win);
    const u16* kwb = kw + wbase * 256 * 128;
    const u16* qwb = qw + wbase * 256 * 128;
    const u16* vtb = vt + wbase * 128 * 256;

    bf16x8 af[4];
    const u16* qrow = qwb + (size_t)(q0 + w * 16 + lm) * 128;
#pragma unroll
    for (int kt = 0; kt < 4; ++kt)
        af[kt] = *(const bf16x8*)(qrow + kt * 32 + q * 8);

    f32x4 s[16];
#pragma unroll
    for (int nt = 0; nt < 16; ++nt) { f32x4 z = {0.f, 0.f, 0.f, 0.f}; s[nt] = z; }
#pragma unroll
    for (int kt = 0; kt < 4; ++kt)
#pragma unroll
        for (int nt = 0; nt < 16; ++nt) {
            bf16x8 bf = *(const bf16x8*)(kwb + (size_t)(nt * 16 + lm) * 128 + kt * 32 + q * 8);
            s[nt] = __builtin_amdgcn_mfma_f32_16x16x32_bf16(af[kt], bf, s[nt], 0, 0, 0);
        }

    int idk[16];
#pragma unroll
    for (int nt = 0; nt < 16; ++nt) {
        int rh = (wi == 7) ? ((nt >= 8) ? 2 : 1) : 0;
        int rw = (wj == 7) ? ((lm >= 8) ? 2 : 1) : 0;
        idk[nt] = rh * 3 + rw;
    }
    const float scale = 0.08838834764831845f;
#pragma unroll
    for (int r = 0; r < 4; ++r) {
        int tq = q0 + w * 16 + q * 4 + r;
        int iq = tq >> 4, jq = tq & 15;
        int rhq = (wi == 7) ? ((iq >= 8) ? 2 : 1) : 0;
        int rwq = (wj == 7) ? ((jq >= 8) ? 2 : 1) : 0;
        int idq = rhq * 3 + rwq;
        float sv[16];
        float mx = -1e30f;
#pragma unroll
        for (int nt = 0; nt < 16; ++nt) {
            float x = s[nt][r] * scale + ((idq != idk[nt]) ? -100.f : 0.f);
            sv[nt] = x; mx = fmaxf(mx, x);
        }
        mx = fmaxf(mx, __shfl_xor(mx, 1));
        mx = fmaxf(mx, __shfl_xor(mx, 2));
        mx = fmaxf(mx, __shfl_xor(mx, 4));
        mx = fmaxf(mx, __shfl_xor(mx, 8));
        float sum = 0.f;
#pragma unroll
        for (int nt = 0; nt < 16; ++nt) { float e = __expf(sv[nt] - mx); sv[nt] = e; sum += e; }
        sum += __shfl_xor(sum, 1);
        sum += __shfl_xor(sum, 2);
        sum += __shfl_xor(sum, 4);
        sum += __shfl_xor(sum, 8);
        float inv = 1.0f / sum;
#pragma unroll
        for (int nt = 0; nt < 16; ++nt)
            Ps[(w * 16 + q * 4 + r) * 264 + nt * 16 + lm] = f2b(sv[nt] * inv);
    }
    __syncthreads();

    f32x4 o[8];
#pragma unroll
    for (int nt = 0; nt < 8; ++nt) { f32x4 z = {0.f, 0.f, 0.f, 0.f}; o[nt] = z; }
#pragma unroll
    for (int tt = 0; tt < 8; ++tt) {
        bf16x8 pf = *(const bf16x8*)(Ps + (w * 16 + lm) * 264 + tt * 32 + q * 8);
#pragma unroll
        for (int nt = 0; nt < 8; ++nt) {
            bf16x8 vf = *(const bf16x8*)(vtb + (size_t)(nt * 16 + lm) * 256 + tt * 32 + q * 8);
            o[nt] = __builtin_amdgcn_mfma_f32_16x16x32_bf16(pf, vf, o[nt], 0, 0, 0);
        }
    }
#pragma unroll
    for (int r = 0; r < 4; ++r) {
        int t = q0 + w * 16 + q * 4 + r;
        int i = t >> 4, j = t & 15;
        int h = (wi * 16 + i + 8) & 127;
        int w2 = (wj * 16 + j + 8) & 127;
        size_t orow = ((size_t)b * 16384 + h * 128 + w2) * 128;
#pragma unroll
        for (int nt = 0; nt < 8; ++nt)
            om[orow + nt * 16 + lm] = f2b(o[nt][r]);
    }
}

// ---------------------------------------------------------------------------
// Prep: transpose + fp32->bf16 weights; fp32->bf16 activations.
// ---------------------------------------------------------------------------
__global__ void prep_w(const float* __restrict__ Wq, const float* __restrict__ Wk,
                       const float* __restrict__ Wv, const float* __restrict__ Wm,
                       const float* __restrict__ W1, const float* __restrict__ W2,
                       u16* __restrict__ ws)
{
    int idx = blockIdx.x * 256 + threadIdx.x;
    if (idx < 65536) {                       // Wq,Wk,Wv,Wm: 128x128
        int m = idx >> 14, e = idx & 16383;
        const float* src = (m == 0) ? Wq : (m == 1) ? Wk : (m == 2) ? Wv : Wm;
        int k = e >> 7, n = e & 127;
        ws[m * 16384 + n * 128 + k] = f2b(src[e]);
    } else if (idx < 65536 + 262144) {       // W1: (256,1024) -> (1024,256)
        int e = idx - 65536;
        int k = e >> 10, n = e & 1023;
        ws[65536 + n * 256 + k] = f2b(W1[e]);
    } else {                                  // W2: (1024,128) -> (128,1024)
        int e = idx - (65536 + 262144);
        int k = e >> 7, n = e & 127;
        ws[327680 + n * 1024 + k] = f2b(W2[e]);
    }
}

__global__ void prep_x(const float* __restrict__ src, const float* __restrict__ tgt,
                       u16* __restrict__ srcb, u16* __restrict__ tgtb)
{
    int idx = blockIdx.x * 256 + threadIdx.x;   // 0..2097151
    const float* s; u16* d; int i;
    if (idx < 1048576) { s = src; d = srcb; i = idx * 4; }
    else               { s = tgt; d = tgtb; i = (idx - 1048576) * 4; }
    f32x4 v = *(const f32x4*)(s + i);
    u16x4 o; o[0] = f2b(v[0]); o[1] = f2b(v[1]); o[2] = f2b(v[2]); o[3] = f2b(v[3]);
    *(u16x4*)(d + i) = o;
}

// ---------------------------------------------------------------------------
// Workspace layout (u16 element offsets); total 59,179,008 u16 = ~113 MB.
// ---------------------------------------------------------------------------
#define OFF_WQT  0u            // concat [WqT;WkT;WvT] 3x(128x128)
#define OFF_WMT  49152u
#define OFF_W1T  65536u
#define OFF_W2T  327680u
#define OFF_SRCB 458752u
#define OFF_TGTB 4653056u
#define OFF_QW   8847360u
#define OFF_KW   13041664u
#define OFF_VWT  17235968u
#define OFF_ATTN 21430272u
#define OFF_HID  25624576u     // bf16 32768x1024, ends 59179008
#define OFF_MSGB 8847360u      // bf16 msg over QW (dead after attn)

extern "C" void kernel_launch(void* const* d_in, const int* in_sizes, int n_in,
                              void* d_out, int out_size, void* d_ws, size_t ws_size,
                              hipStream_t stream)
{
    (void)in_sizes; (void)n_in; (void)out_size; (void)ws_size;
    const float* source = (const float*)d_in[0];
    const float* target = (const float*)d_in[1];
    const float* Wq = (const float*)d_in[2];
    const float* Wk = (const float*)d_in[3];
    const float* Wv = (const float*)d_in[4];
    const float* Wm = (const float*)d_in[5];
    const float* g1 = (const float*)d_in[6];
    const float* b1 = (const float*)d_in[7];
    const float* W1 = (const float*)d_in[8];
    const float* W2 = (const float*)d_in[9];
    const float* g2 = (const float*)d_in[10];
    const float* b2 = (const float*)d_in[11];
    u16* ws = (u16*)d_ws;
    float* out = (float*)d_out;

    prep_w<<<1792, 256, 0, stream>>>(Wq, Wk, Wv, Wm, W1, W2, ws);
    prep_x<<<8192, 256, 0, stream>>>(source, target, ws + OFF_SRCB, ws + OFF_TGTB);
    // fused q/k/v projections into window layouts (v transposed per window)
    gemm_qkv<<<dim3(256, 3), 256, 0, stream>>>(
        ws + OFF_SRCB, ws + OFF_TGTB, ws + OFF_WQT,
        ws + OFF_QW, ws + OFF_KW, ws + OFF_VWT);
    // windowed attention -> source-order rows (bf16)
    attn_k<<<512, 256, 0, stream>>>(ws + OFF_QW, ws + OFF_KW, ws + OFF_VWT, ws + OFF_ATTN);
    // message = LN(attn @ Wm)  [LN fused into GEMM epilogue, bf16 out]
    gemm_ln<false><<<512, 256, 0, stream>>>(
        ws + OFF_ATTN, ws + OFF_WMT, g1, b1, nullptr, (void*)(ws + OFF_MSGB), 128);
    // ffn1: gelu(concat(src,msg) @ W1) -> bf16 HID
    gemm_ffn1<<<dim3(256, 8), 256, 0, stream>>>(
        ws + OFF_SRCB, ws + OFF_MSGB, ws + OFF_W1T, ws + OFF_HID);
    // ffn2 + LN + residual -> fp32 output
    gemm_ln<true><<<512, 256, 0, stream>>>(
        ws + OFF_HID, ws + OFF_W2T, g2, b2, source, (void*)out, 1024);
}

// Round 5
// 232.817 us; speedup vs baseline: 1.5238x; 1.0043x over previous
//
#include <hip/hip_runtime.h>
#include <math.h>
#include <stdint.h>

// ---------------------------------------------------------------------------
// TransformerLayer (Swin-style) on MI355X. FP32 I/O; bf16 MFMA internals.
// B=2, H=W=128, C=128, NS=8 -> 64 windows x 256 tokens; HID=1024.
// R5: K-resident LDS tiles (kill per-iter barrier drain: R4 FFN1 had KT=8,
//     77 cyc MFMA vs ~400 cyc vmcnt drain per iter). FFN1 BK=128 (KT=2),
//     QKV fully resident, gemm_ln reg-space LN stats (no fp32 LDS tile),
//     attn coalesced output via Ts overlay, prep merged.
// ---------------------------------------------------------------------------

typedef unsigned short u16;
typedef __attribute__((ext_vector_type(8))) short bf16x8;   // 8 bf16 (4 VGPRs)
typedef __attribute__((ext_vector_type(4))) float f32x4;
typedef __attribute__((ext_vector_type(4))) short u16x4;

__device__ __forceinline__ u16 f2b(float f) {
    unsigned int i = __float_as_uint(f);
    unsigned int r = (i + 0x7fffu + ((i >> 16) & 1u)) >> 16;
    return (u16)r;
}

// exact-gelu via Abramowitz-Stegun 7.1.26 erf (max err 1.5e-7)
__device__ __forceinline__ float fast_gelu(float x) {
    float y = fabsf(x) * 0.70710678118f;
    float t = __builtin_amdgcn_rcpf(fmaf(0.3275911f, y, 1.0f));
    float p = fmaf(fmaf(fmaf(fmaf(1.061405429f, t, -1.453152027f), t,
                             1.421413741f), t, -0.284496736f), t, 0.254829592f) * t;
    float e = __expf(-y * y);
    float erf_abs = fmaf(-p, e, 1.0f);
    float s = copysignf(erf_abs, x);
    return 0.5f * x * (1.0f + s);
}

// 16B async global->LDS (m97-verified). LDS dest wave-uniform base + lane*16.
__device__ __forceinline__ void cp16(const void* g, void* l) {
    auto* gp = reinterpret_cast<const __attribute__((address_space(1))) unsigned int*>(
        reinterpret_cast<uintptr_t>(g));
    auto* lp = reinterpret_cast<__attribute__((address_space(3))) unsigned int*>(
        reinterpret_cast<uintptr_t>(l));
    __builtin_amdgcn_global_load_lds(gp, lp, 16, 0, 0);
}

// window row (b*16384 + win*256 + t) -> source-order row (b*16384 + h*128 + w)
__device__ __forceinline__ int win_map(int gm) {
    int b = gm >> 14, rr = gm & 16383;
    int win = rr >> 8, t = rr & 255;
    int wi = win >> 3, wj = win & 7, i = t >> 4, j = t & 15;
    int h = (wi * 16 + i + 8) & 127;
    int w = (wj * 16 + j + 8) & 127;
    return (b << 14) + h * 128 + w;
}

// ---------------------------------------------------------------------------
// Fused QKV: grid (256, 3). y=0: q=src@Wq, y=1: k=tgt@Wk (window layouts),
// y=2: v=tgt@Wv stored transposed per window. K=128 fully LDS-resident:
// one barrier, then 64 uninterrupted MFMA. Bt = concat [WqT;WkT;WvT].
// ---------------------------------------------------------------------------
__global__ __launch_bounds__(256, 2)
void gemm_qkv(const u16* __restrict__ srcb, const u16* __restrict__ tgtb,
              const u16* __restrict__ Bt, u16* __restrict__ qw,
              u16* __restrict__ kw, u16* __restrict__ vwt)
{
    __shared__ __align__(16) u16 SMEM[32768];   // As[4][128][32] | Bs[4][128][32]
    u16* As = SMEM;
    u16* Bs = SMEM + 16384;
    u16* Ts = SMEM;                              // 128x136 epilogue overlay

    const int tid = threadIdx.x;
    const int w = tid >> 6, lane = tid & 63;
    const int lm = lane & 15, q = lane >> 4;
    const int wm = w >> 1, wn = w & 1;
    const int m0 = blockIdx.x * 128;
    const int y = blockIdx.y;
    const u16* Ab = (y == 0) ? srcb : tgtb;

#pragma unroll
    for (int s = 0; s < 4; ++s)
#pragma unroll
        for (int i = 0; i < 2; ++i) {
            int row = w * 32 + i * 16 + (lane >> 2);
            int kc = s * 32 + (lane & 3) * 8;
            cp16(Ab + (size_t)win_map(m0 + row) * 128 + kc,
                 (void*)(As + (s * 128 + w * 32 + i * 16) * 32));
            cp16(Bt + (size_t)(y * 128 + row) * 128 + kc,
                 (void*)(Bs + (s * 128 + w * 32 + i * 16) * 32));
        }
    __syncthreads();

    f32x4 acc[4][4] = {};
#pragma unroll
    for (int s = 0; s < 4; ++s) {
        bf16x8 af[4], bfr[4];
#pragma unroll
        for (int t = 0; t < 4; ++t)
            af[t] = *(const bf16x8*)(As + (s * 128 + wm * 64 + t * 16 + lm) * 32 + q * 8);
#pragma unroll
        for (int t = 0; t < 4; ++t)
            bfr[t] = *(const bf16x8*)(Bs + (s * 128 + wn * 64 + t * 16 + lm) * 32 + q * 8);
#pragma unroll
        for (int mt = 0; mt < 4; ++mt)
#pragma unroll
            for (int nt = 0; nt < 4; ++nt)
                acc[mt][nt] = __builtin_amdgcn_mfma_f32_16x16x32_bf16(
                    af[mt], bfr[nt], acc[mt][nt], 0, 0, 0);
    }

    __syncthreads();
#pragma unroll
    for (int mt = 0; mt < 4; ++mt)
#pragma unroll
        for (int nt = 0; nt < 4; ++nt)
#pragma unroll
            for (int r = 0; r < 4; ++r) {
                int rowl = wm * 64 + mt * 16 + q * 4 + r;
                int col = wn * 64 + nt * 16 + lm;
                int idx = (y == 2) ? col * 136 + rowl : rowl * 136 + col;
                Ts[idx] = f2b(acc[mt][nt][r]);
            }
    __syncthreads();
    const int c8 = (tid & 15) * 8;
#pragma unroll
    for (int i = 0; i < 8; ++i) {
        int rr = i * 16 + (tid >> 4);
        bf16x8 t = *(const bf16x8*)(Ts + rr * 136 + c8);
        if (y == 2) {
            int wix = m0 >> 8, tok0 = m0 & 255;   // vwT[(b*64+win)*128+ch][tok]
            *(bf16x8*)(vwt + (size_t)wix * 32768 + (size_t)rr * 256 + tok0 + c8) = t;
        } else {
            u16* Cv = (y == 0) ? qw : kw;
            *(bf16x8*)(Cv + (size_t)(m0 + rr) * 128 + c8) = t;
        }
    }
}

// ---------------------------------------------------------------------------
// FFN1: gelu(concat(src,msg) @ W1) -> bf16 HID. BM=128, BN=128, BK=128
// (KT=2, 64 MFMA per barrier pair). LDS 64KB -> 2 blocks/CU.
// ---------------------------------------------------------------------------
__global__ __launch_bounds__(256, 2)
void gemm_ffn1(const u16* __restrict__ A0, const u16* __restrict__ A1,
               const u16* __restrict__ Bt, u16* __restrict__ C)
{
    __shared__ __align__(16) u16 SMEM[32768];
    u16* As = SMEM;
    u16* Bs = SMEM + 16384;
    u16* Ts = SMEM;

    const int tid = threadIdx.x;
    const int w = tid >> 6, lane = tid & 63;
    const int lm = lane & 15, q = lane >> 4;
    const int wm = w >> 1, wn = w & 1;
    const int m0 = blockIdx.x * 128, n0 = blockIdx.y * 128;

    f32x4 acc[4][4] = {};
#pragma unroll
    for (int kt2 = 0; kt2 < 2; ++kt2) {
        __syncthreads();
        const u16* Ab = kt2 ? A1 : A0;   // cat(src, msg): K halves
#pragma unroll
        for (int s = 0; s < 4; ++s)
#pragma unroll
            for (int i = 0; i < 2; ++i) {
                int row = w * 32 + i * 16 + (lane >> 2);
                int kc = s * 32 + (lane & 3) * 8;
                cp16(Ab + (size_t)(m0 + row) * 128 + kc,
                     (void*)(As + (s * 128 + w * 32 + i * 16) * 32));
                cp16(Bt + (size_t)(n0 + row) * 256 + kt2 * 128 + kc,
                     (void*)(Bs + (s * 128 + w * 32 + i * 16) * 32));
            }
        __syncthreads();
#pragma unroll
        for (int s = 0; s < 4; ++s) {
            bf16x8 af[4], bfr[4];
#pragma unroll
            for (int t = 0; t < 4; ++t)
                af[t] = *(const bf16x8*)(As + (s * 128 + wm * 64 + t * 16 + lm) * 32 + q * 8);
#pragma unroll
            for (int t = 0; t < 4; ++t)
                bfr[t] = *(const bf16x8*)(Bs + (s * 128 + wn * 64 + t * 16 + lm) * 32 + q * 8);
#pragma unroll
            for (int mt = 0; mt < 4; ++mt)
#pragma unroll
                for (int nt = 0; nt < 4; ++nt)
                    acc[mt][nt] = __builtin_amdgcn_mfma_f32_16x16x32_bf16(
                        af[mt], bfr[nt], acc[mt][nt], 0, 0, 0);
        }
    }

    __syncthreads();
#pragma unroll
    for (int mt = 0; mt < 4; ++mt)
#pragma unroll
        for (int nt = 0; nt < 4; ++nt)
#pragma unroll
            for (int r = 0; r < 4; ++r) {
                int rowl = wm * 64 + mt * 16 + q * 4 + r;
                int col = wn * 64 + nt * 16 + lm;
                Ts[rowl * 136 + col] = f2b(fast_gelu(acc[mt][nt][r]));
            }
    __syncthreads();
    const int c8 = (tid & 15) * 8;
#pragma unroll
    for (int i = 0; i < 8; ++i) {
        int rr = i * 16 + (tid >> 4);
        bf16x8 t = *(const bf16x8*)(Ts + rr * 136 + c8);
        *(bf16x8*)(C + (size_t)(m0 + rr) * 1024 + n0 + c8) = t;
    }
}

// ---------------------------------------------------------------------------
// N=128 GEMM + fused LayerNorm. BM=64, BK=128 streaming (KSTAGES k-chunks of
// 128). LN stats in registers (shuffle over lm) + 1KB LDS exchange between
// wn halves. RESID=false: bf16 out via Ts. RESID=true: fp32 out = resid+LN.
// K = KSTAGES*128. LDS 50KB -> 3 blocks/CU.
// ---------------------------------------------------------------------------
template <int KSTAGES, bool RESID>
__global__ __launch_bounds__(256, 3)
void gemm_ln(const u16* __restrict__ A, const u16* __restrict__ Bt,
             const float* __restrict__ g, const float* __restrict__ bb,
             const float* __restrict__ resid, void* __restrict__ outv)
{
    __shared__ __align__(16) u16 SMEM[25088];
    u16* As = SMEM;                         // [4][64][32]  (8192)
    u16* Bs = SMEM + 8192;                  // [4][128][32] (16384)
    float* stats = (float*)(SMEM + 24576);  // [64][4]: wn0.s,wn0.s2,wn1.s,wn1.s2
    u16* Ts = SMEM;                         // 64x136 overlay (msg path)

    const int tid = threadIdx.x;
    const int w = tid >> 6, lane = tid & 63;
    const int lm = lane & 15, q = lane >> 4;
    const int wm = w >> 1, wn = w & 1;
    const int m0 = blockIdx.x * 64;
    const int K = KSTAGES * 128;

    f32x4 acc[2][4] = {};
#pragma unroll
    for (int kt2 = 0; kt2 < KSTAGES; ++kt2) {
        __syncthreads();
#pragma unroll
        for (int s = 0; s < 4; ++s) {
            int kc = kt2 * 128 + s * 32 + (lane & 3) * 8;
            int arow = w * 16 + (lane >> 2);
            cp16(A + (size_t)(m0 + arow) * K + kc,
                 (void*)(As + (s * 64 + w * 16) * 32));
#pragma unroll
            for (int i = 0; i < 2; ++i) {
                int brow = w * 32 + i * 16 + (lane >> 2);
                cp16(Bt + (size_t)brow * K + kc,
                     (void*)(Bs + (s * 128 + w * 32 + i * 16) * 32));
            }
        }
        __syncthreads();
#pragma unroll
        for (int s = 0; s < 4; ++s) {
            bf16x8 af[2], bfr[4];
#pragma unroll
            for (int t = 0; t < 2; ++t)
                af[t] = *(const bf16x8*)(As + (s * 64 + wm * 32 + t * 16 + lm) * 32 + q * 8);
#pragma unroll
            for (int t = 0; t < 4; ++t)
                bfr[t] = *(const bf16x8*)(Bs + (s * 128 + wn * 64 + t * 16 + lm) * 32 + q * 8);
#pragma unroll
            for (int mt = 0; mt < 2; ++mt)
#pragma unroll
                for (int nt = 0; nt < 4; ++nt)
                    acc[mt][nt] = __builtin_amdgcn_mfma_f32_16x16x32_bf16(
                        af[mt], bfr[nt], acc[mt][nt], 0, 0, 0);
        }
    }

    // register-space LN stats: row = wm*32 + mt*16 + q*4 + r, wave holds 64 cols
#pragma unroll
    for (int mt = 0; mt < 2; ++mt)
#pragma unroll
        for (int r = 0; r < 4; ++r) {
            float s1 = 0.f, s2 = 0.f;
#pragma unroll
            for (int nt = 0; nt < 4; ++nt) {
                float v = acc[mt][nt][r];
                s1 += v; s2 += v * v;
            }
            s1 += __shfl_xor(s1, 1); s2 += __shfl_xor(s2, 1);
            s1 += __shfl_xor(s1, 2); s2 += __shfl_xor(s2, 2);
            s1 += __shfl_xor(s1, 4); s2 += __shfl_xor(s2, 4);
            s1 += __shfl_xor(s1, 8); s2 += __shfl_xor(s2, 8);
            if (lm == 0) {
                int row = wm * 32 + mt * 16 + q * 4 + r;
                stats[row * 4 + wn * 2] = s1;
                stats[row * 4 + wn * 2 + 1] = s2;
            }
        }
    __syncthreads();

    // per-col gamma/beta (col = wn*64 + nt*16 + lm)
    float gv[4], bv[4];
#pragma unroll
    for (int nt = 0; nt < 4; ++nt) {
        int col = wn * 64 + nt * 16 + lm;
        gv[nt] = g[col]; bv[nt] = bb[col];
    }

#pragma unroll
    for (int mt = 0; mt < 2; ++mt)
#pragma unroll
        for (int r = 0; r < 4; ++r) {
            int row = wm * 32 + mt * 16 + q * 4 + r;
            f32x4 st = *(const f32x4*)(stats + row * 4);
            float mean = (st[0] + st[2]) * (1.f / 128.f);
            float var = fmaxf((st[1] + st[3]) * (1.f / 128.f) - mean * mean, 0.f);
            float rs = rsqrtf(var + 1e-5f);
#pragma unroll
            for (int nt = 0; nt < 4; ++nt) {
                int col = wn * 64 + nt * 16 + lm;
                float yv = (acc[mt][nt][r] - mean) * rs * gv[nt] + bv[nt];
                if (RESID) {
                    size_t gi = (size_t)(m0 + row) * 128 + col;
                    ((float*)outv)[gi] = yv + resid[gi];   // 16x4B = full sectors
                } else {
                    Ts[row * 136 + col] = f2b(yv);
                }
            }
        }
    if (!RESID) {
        __syncthreads();
        const int c8 = (tid & 15) * 8;
#pragma unroll
        for (int i = 0; i < 4; ++i) {
            int rr = i * 16 + (tid >> 4);
            bf16x8 t = *(const bf16x8*)(Ts + rr * 136 + c8);
            *(bf16x8*)((u16*)outv + (size_t)(m0 + rr) * 128 + c8) = t;
        }
    }
}

// ---------------------------------------------------------------------------
// Windowed attention. LDS = P (33KB); K/V frags from global (L2-resident).
// One block = 64 Q rows of one window; grid = 2*64*4. Coalesced output via
// Ts overlay on Ps.
// ---------------------------------------------------------------------------
__global__ __launch_bounds__(256)
void attn_k(const u16* __restrict__ qw, const u16* __restrict__ kw,
            const u16* __restrict__ vt, u16* __restrict__ om)
{
    __shared__ __align__(16) u16 Ps[64 * 264];

    const int tid = threadIdx.x, w = tid >> 6, lane = tid & 63;
    const int lm = lane & 15, q = lane >> 4;
    const int bid = blockIdx.x;
    const int qc = bid & 3, win = (bid >> 2) & 63, b = bid >> 8;
    const int wi = win >> 3, wj = win & 7;
    const int q0 = qc * 64;
    const size_t wbase = (size_t)(b * 64 + win);
    const u16* kwb = kw + wbase * 256 * 128;
    const u16* qwb = qw + wbase * 256 * 128;
    const u16* vtb = vt + wbase * 128 * 256;

    bf16x8 af[4];
    const u16* qrow = qwb + (size_t)(q0 + w * 16 + lm) * 128;
#pragma unroll
    for (int kt = 0; kt < 4; ++kt)
        af[kt] = *(const bf16x8*)(qrow + kt * 32 + q * 8);

    f32x4 s[16];
#pragma unroll
    for (int nt = 0; nt < 16; ++nt) { f32x4 z = {0.f, 0.f, 0.f, 0.f}; s[nt] = z; }
#pragma unroll
    for (int kt = 0; kt < 4; ++kt)
#pragma unroll
        for (int nt = 0; nt < 16; ++nt) {
            bf16x8 bf = *(const bf16x8*)(kwb + (size_t)(nt * 16 + lm) * 128 + kt * 32 + q * 8);
            s[nt] = __builtin_amdgcn_mfma_f32_16x16x32_bf16(af[kt], bf, s[nt], 0, 0, 0);
        }

    int idk[16];
#pragma unroll
    for (int nt = 0; nt < 16; ++nt) {
        int rh = (wi == 7) ? ((nt >= 8) ? 2 : 1) : 0;
        int rw = (wj == 7) ? ((lm >= 8) ? 2 : 1) : 0;
        idk[nt] = rh * 3 + rw;
    }
    const float scale = 0.08838834764831845f;
#pragma unroll
    for (int r = 0; r < 4; ++r) {
        int tq = q0 + w * 16 + q * 4 + r;
        int iq = tq >> 4, jq = tq & 15;
        int rhq = (wi == 7) ? ((iq >= 8) ? 2 : 1) : 0;
        int rwq = (wj == 7) ? ((jq >= 8) ? 2 : 1) : 0;
        int idq = rhq * 3 + rwq;
        float sv[16];
        float mx = -1e30f;
#pragma unroll
        for (int nt = 0; nt < 16; ++nt) {
            float x = s[nt][r] * scale + ((idq != idk[nt]) ? -100.f : 0.f);
            sv[nt] = x; mx = fmaxf(mx, x);
        }
        mx = fmaxf(mx, __shfl_xor(mx, 1));
        mx = fmaxf(mx, __shfl_xor(mx, 2));
        mx = fmaxf(mx, __shfl_xor(mx, 4));
        mx = fmaxf(mx, __shfl_xor(mx, 8));
        float sum = 0.f;
#pragma unroll
        for (int nt = 0; nt < 16; ++nt) { float e = __expf(sv[nt] - mx); sv[nt] = e; sum += e; }
        sum += __shfl_xor(sum, 1);
        sum += __shfl_xor(sum, 2);
        sum += __shfl_xor(sum, 4);
        sum += __shfl_xor(sum, 8);
        float inv = 1.0f / sum;
#pragma unroll
        for (int nt = 0; nt < 16; ++nt)
            Ps[(w * 16 + q * 4 + r) * 264 + nt * 16 + lm] = f2b(sv[nt] * inv);
    }
    __syncthreads();

    f32x4 o[8];
#pragma unroll
    for (int nt = 0; nt < 8; ++nt) { f32x4 z = {0.f, 0.f, 0.f, 0.f}; o[nt] = z; }
#pragma unroll
    for (int tt = 0; tt < 8; ++tt) {
        bf16x8 pf = *(const bf16x8*)(Ps + (w * 16 + lm) * 264 + tt * 32 + q * 8);
#pragma unroll
        for (int nt = 0; nt < 8; ++nt) {
            bf16x8 vf = *(const bf16x8*)(vtb + (size_t)(nt * 16 + lm) * 256 + tt * 32 + q * 8);
            o[nt] = __builtin_amdgcn_mfma_f32_16x16x32_bf16(pf, vf, o[nt], 0, 0, 0);
        }
    }

    // coalesced output: stage rows in Ts (overlay Ps), then 16B/lane stores
    __syncthreads();
    u16* Ts = Ps;   // 64x136
#pragma unroll
    for (int r = 0; r < 4; ++r) {
        int rl = w * 16 + q * 4 + r;
#pragma unroll
        for (int nt = 0; nt < 8; ++nt)
            Ts[rl * 136 + nt * 16 + lm] = f2b(o[nt][r]);
    }
    __syncthreads();
    const int c8 = (tid & 15) * 8;
#pragma unroll
    for (int i = 0; i < 4; ++i) {
        int rr = i * 16 + (tid >> 4);
        int t = q0 + rr;
        int ii = t >> 4, jj = t & 15;
        int h = (wi * 16 + ii + 8) & 127;
        int w2 = (wj * 16 + jj + 8) & 127;
        bf16x8 v = *(const bf16x8*)(Ts + rr * 136 + c8);
        *(bf16x8*)(om + ((size_t)b * 16384 + h * 128 + w2) * 128 + c8) = v;
    }
}

// ---------------------------------------------------------------------------
// Prep (merged): weight transpose+cast (blocks 0..1791), activation cast
// (blocks 1792..9983).
// ---------------------------------------------------------------------------
__global__ void prep_all(const float* __restrict__ Wq, const float* __restrict__ Wk,
                         const float* __restrict__ Wv, const float* __restrict__ Wm,
                         const float* __restrict__ W1, const float* __restrict__ W2,
                         const float* __restrict__ src, const float* __restrict__ tgt,
                         u16* __restrict__ ws, u16* __restrict__ srcb,
                         u16* __restrict__ tgtb)
{
    int bx = blockIdx.x;
    if (bx < 1792) {
        int idx = bx * 256 + threadIdx.x;
        if (idx < 65536) {                       // Wq,Wk,Wv,Wm: 128x128
            int m = idx >> 14, e = idx & 16383;
            const float* sp = (m == 0) ? Wq : (m == 1) ? Wk : (m == 2) ? Wv : Wm;
            int k = e >> 7, n = e & 127;
            ws[m * 16384 + n * 128 + k] = f2b(sp[e]);
        } else if (idx < 65536 + 262144) {       // W1: (256,1024) -> (1024,256)
            int e = idx - 65536;
            int k = e >> 10, n = e & 1023;
            ws[65536 + n * 256 + k] = f2b(W1[e]);
        } else {                                  // W2: (1024,128) -> (128,1024)
            int e = idx - (65536 + 262144);
            int k = e >> 7, n = e & 127;
            ws[327680 + n * 1024 + k] = f2b(W2[e]);
        }
    } else {
        int idx = (bx - 1792) * 256 + threadIdx.x;   // 0..2097151
        const float* s; u16* d; int i;
        if (idx < 1048576) { s = src; d = srcb; i = idx * 4; }
        else               { s = tgt; d = tgtb; i = (idx - 1048576) * 4; }
        f32x4 v = *(const f32x4*)(s + i);
        u16x4 o; o[0] = f2b(v[0]); o[1] = f2b(v[1]); o[2] = f2b(v[2]); o[3] = f2b(v[3]);
        *(u16x4*)(d + i) = o;
    }
}

// ---------------------------------------------------------------------------
// Workspace layout (u16 element offsets); total 59,179,008 u16 = ~113 MB.
// ---------------------------------------------------------------------------
#define OFF_WQT  0u            // concat [WqT;WkT;WvT] 3x(128x128)
#define OFF_WMT  49152u
#define OFF_W1T  65536u
#define OFF_W2T  327680u
#define OFF_SRCB 458752u
#define OFF_TGTB 4653056u
#define OFF_QW   8847360u
#define OFF_KW   13041664u
#define OFF_VWT  17235968u
#define OFF_ATTN 21430272u
#define OFF_HID  25624576u     // bf16 32768x1024, ends 59179008
#define OFF_MSGB 8847360u      // bf16 msg over QW (dead after attn)

extern "C" void kernel_launch(void* const* d_in, const int* in_sizes, int n_in,
                              void* d_out, int out_size, void* d_ws, size_t ws_size,
                              hipStream_t stream)
{
    (void)in_sizes; (void)n_in; (void)out_size; (void)ws_size;
    const float* source = (const float*)d_in[0];
    const float* target = (const float*)d_in[1];
    const float* Wq = (const float*)d_in[2];
    const float* Wk = (const float*)d_in[3];
    const float* Wv = (const float*)d_in[4];
    const float* Wm = (const float*)d_in[5];
    const float* g1 = (const float*)d_in[6];
    const float* b1 = (const float*)d_in[7];
    const float* W1 = (const float*)d_in[8];
    const float* W2 = (const float*)d_in[9];
    const float* g2 = (const float*)d_in[10];
    const float* b2 = (const float*)d_in[11];
    u16* ws = (u16*)d_ws;
    float* out = (float*)d_out;

    prep_all<<<9984, 256, 0, stream>>>(Wq, Wk, Wv, Wm, W1, W2, source, target,
                                       ws, ws + OFF_SRCB, ws + OFF_TGTB);
    gemm_qkv<<<dim3(256, 3), 256, 0, stream>>>(
        ws + OFF_SRCB, ws + OFF_TGTB, ws + OFF_WQT,
        ws + OFF_QW, ws + OFF_KW, ws + OFF_VWT);
    attn_k<<<512, 256, 0, stream>>>(ws + OFF_QW, ws + OFF_KW, ws + OFF_VWT, ws + OFF_ATTN);
    // message = LN(attn @ Wm) -> bf16 (K=128 resident)
    gemm_ln<1, false><<<512, 256, 0, stream>>>(
        ws + OFF_ATTN, ws + OFF_WMT, g1, b1, nullptr, (void*)(ws + OFF_MSGB));
    // ffn1: gelu(cat(src,msg) @ W1) -> bf16 HID
    gemm_ffn1<<<dim3(256, 8), 256, 0, stream>>>(
        ws + OFF_SRCB, ws + OFF_MSGB, ws + OFF_W1T, ws + OFF_HID);
    // ffn2 + LN + residual -> fp32 out (K=1024, KT=8 streaming)
    gemm_ln<8, true><<<512, 256, 0, stream>>>(
        ws + OFF_HID, ws + OFF_W2T, g2, b2, source, (void*)out);
}

// Round 6
// 232.461 us; speedup vs baseline: 1.5261x; 1.0015x over previous
//
#include <hip/hip_runtime.h>
#include <math.h>
#include <stdint.h>

// ---------------------------------------------------------------------------
// TransformerLayer (Swin-style) on MI355X. FP32 I/O; bf16 MFMA internals.
// B=2, H=W=128, C=128, NS=8 -> 64 windows x 256 tokens; HID=1024.
// R6: FFN1 rebuilt on 32x32x16 MFMA with direct full-sector bf16 stores
//     (no Ts/bank conflicts) + 1-transcendental gelu (R5 was epilogue-
//     VALU-bound: 2 quarter-rate transcendentals x 64 elems ~ 2430 cyc/wave).
//     msg-proj+LN fused INTO attention (deletes a dispatch + 16MB roundtrip).
//     prep transposes write-coalesced.
// ---------------------------------------------------------------------------

typedef unsigned short u16;
typedef __attribute__((ext_vector_type(8))) short bf16x8;   // 8 bf16 (4 VGPRs)
typedef __attribute__((ext_vector_type(4))) float f32x4;
typedef __attribute__((ext_vector_type(16))) float f32x16;  // 32x32 accumulator
typedef __attribute__((ext_vector_type(4))) short u16x4;

__device__ __forceinline__ u16 f2b(float f) {
    unsigned int i = __float_as_uint(f);
    unsigned int r = (i + 0x7fffu + ((i >> 16) & 1u)) >> 16;
    return (u16)r;
}

// gelu via A-S 7.1.28 erf (|eps|<=5e-4): gelu(x) = relu(x) - 0.5|x|/u^4,
// u = 1 + y(a1 + y(a2 + y(a3 + y a4))), y = |x|/sqrt(2). ONE transcendental.
__device__ __forceinline__ float gelu_e(float x) {
    float y = fabsf(x) * 0.70710678118f;
    float u = fmaf(y, fmaf(y, fmaf(y, fmaf(y, 0.078108f, 0.000972f),
                                   0.230389f), 0.278393f), 1.0f);
    u = u * u; u = u * u;
    float r = __builtin_amdgcn_rcpf(u);
    return fmaxf(x, 0.f) - 0.5f * fabsf(x) * r;
}

// 16B async global->LDS (m97-verified). LDS dest wave-uniform base + lane*16.
__device__ __forceinline__ void cp16(const void* g, void* l) {
    auto* gp = reinterpret_cast<const __attribute__((address_space(1))) unsigned int*>(
        reinterpret_cast<uintptr_t>(g));
    auto* lp = reinterpret_cast<__attribute__((address_space(3))) unsigned int*>(
        reinterpret_cast<uintptr_t>(l));
    __builtin_amdgcn_global_load_lds(gp, lp, 16, 0, 0);
}

// window row (b*16384 + win*256 + t) -> source-order row (b*16384 + h*128 + w)
__device__ __forceinline__ int win_map(int gm) {
    int b = gm >> 14, rr = gm & 16383;
    int win = rr >> 8, t = rr & 255;
    int wi = win >> 3, wj = win & 7, i = t >> 4, j = t & 15;
    int h = (wi * 16 + i + 8) & 127;
    int w = (wj * 16 + j + 8) & 127;
    return (b << 14) + h * 128 + w;
}

// ---------------------------------------------------------------------------
// Fused QKV: grid (256, 3). y=0: q=src@Wq, y=1: k=tgt@Wk (window layouts),
// y=2: v=tgt@Wv stored transposed per window. K=128 fully LDS-resident.
// ---------------------------------------------------------------------------
__global__ __launch_bounds__(256, 2)
void gemm_qkv(const u16* __restrict__ srcb, const u16* __restrict__ tgtb,
              const u16* __restrict__ Bt, u16* __restrict__ qw,
              u16* __restrict__ kw, u16* __restrict__ vwt)
{
    __shared__ __align__(16) u16 SMEM[32768];   // As[4][128][32] | Bs[4][128][32]
    u16* As = SMEM;
    u16* Bs = SMEM + 16384;
    u16* Ts = SMEM;                              // 128x136 epilogue overlay

    const int tid = threadIdx.x;
    const int w = tid >> 6, lane = tid & 63;
    const int lm = lane & 15, q = lane >> 4;
    const int wm = w >> 1, wn = w & 1;
    const int m0 = blockIdx.x * 128;
    const int y = blockIdx.y;
    const u16* Ab = (y == 0) ? srcb : tgtb;

#pragma unroll
    for (int s = 0; s < 4; ++s)
#pragma unroll
        for (int i = 0; i < 2; ++i) {
            int row = w * 32 + i * 16 + (lane >> 2);
            int kc = s * 32 + (lane & 3) * 8;
            cp16(Ab + (size_t)win_map(m0 + row) * 128 + kc,
                 (void*)(As + (s * 128 + w * 32 + i * 16) * 32));
            cp16(Bt + (size_t)(y * 128 + row) * 128 + kc,
                 (void*)(Bs + (s * 128 + w * 32 + i * 16) * 32));
        }
    __syncthreads();

    f32x4 acc[4][4] = {};
#pragma unroll
    for (int s = 0; s < 4; ++s) {
        bf16x8 af[4], bfr[4];
#pragma unroll
        for (int t = 0; t < 4; ++t)
            af[t] = *(const bf16x8*)(As + (s * 128 + wm * 64 + t * 16 + lm) * 32 + q * 8);
#pragma unroll
        for (int t = 0; t < 4; ++t)
            bfr[t] = *(const bf16x8*)(Bs + (s * 128 + wn * 64 + t * 16 + lm) * 32 + q * 8);
#pragma unroll
        for (int mt = 0; mt < 4; ++mt)
#pragma unroll
            for (int nt = 0; nt < 4; ++nt)
                acc[mt][nt] = __builtin_amdgcn_mfma_f32_16x16x32_bf16(
                    af[mt], bfr[nt], acc[mt][nt], 0, 0, 0);
    }

    __syncthreads();
#pragma unroll
    for (int mt = 0; mt < 4; ++mt)
#pragma unroll
        for (int nt = 0; nt < 4; ++nt)
#pragma unroll
            for (int r = 0; r < 4; ++r) {
                int rowl = wm * 64 + mt * 16 + q * 4 + r;
                int col = wn * 64 + nt * 16 + lm;
                int idx = (y == 2) ? col * 136 + rowl : rowl * 136 + col;
                Ts[idx] = f2b(acc[mt][nt][r]);
            }
    __syncthreads();
    const int c8 = (tid & 15) * 8;
#pragma unroll
    for (int i = 0; i < 8; ++i) {
        int rr = i * 16 + (tid >> 4);
        bf16x8 t = *(const bf16x8*)(Ts + rr * 136 + c8);
        if (y == 2) {
            int wix = m0 >> 8, tok0 = m0 & 255;   // vwT[(b*64+win)*128+ch][tok]
            *(bf16x8*)(vwt + (size_t)wix * 32768 + (size_t)rr * 256 + tok0 + c8) = t;
        } else {
            u16* Cv = (y == 0) ? qw : kw;
            *(bf16x8*)(Cv + (size_t)(m0 + rr) * 128 + c8) = t;
        }
    }
}

// ---------------------------------------------------------------------------
// FFN1: gelu(concat(src,msg) @ W1) -> bf16 HID. 32x32x16 MFMA, BM=BN=BK=128.
// C/D layout (m74/m101): col=lane&31, row=(r&3)+8*(r>>2)+4*(lane>>5) ->
// direct global_store_short: 32 lanes x 2B = full 64B sectors. No Ts.
// ---------------------------------------------------------------------------
__global__ __launch_bounds__(256, 2)
void gemm_ffn1(const u16* __restrict__ A0, const u16* __restrict__ A1,
               const u16* __restrict__ Bt, u16* __restrict__ C)
{
    __shared__ __align__(16) u16 SMEM[32768];
    u16* As = SMEM;
    u16* Bs = SMEM + 16384;

    const int tid = threadIdx.x;
    const int w = tid >> 6, lane = tid & 63;
    const int l32 = lane & 31, lh = lane >> 5;
    const int wm = w >> 1, wn = w & 1;
    const int m0 = blockIdx.x * 128, n0 = blockIdx.y * 128;

    f32x16 acc[2][2] = {};
#pragma unroll
    for (int kt2 = 0; kt2 < 2; ++kt2) {
        __syncthreads();
        const u16* Ab = kt2 ? A1 : A0;   // cat(src, msg): K halves
#pragma unroll
        for (int s = 0; s < 4; ++s)
#pragma unroll
            for (int i = 0; i < 2; ++i) {
                int row = w * 32 + i * 16 + (lane >> 2);
                int kc = s * 32 + (lane & 3) * 8;
                cp16(Ab + (size_t)(m0 + row) * 128 + kc,
                     (void*)(As + (s * 128 + w * 32 + i * 16) * 32));
                cp16(Bt + (size_t)(n0 + row) * 256 + kt2 * 128 + kc,
                     (void*)(Bs + (s * 128 + w * 32 + i * 16) * 32));
            }
        __syncthreads();
#pragma unroll
        for (int s = 0; s < 4; ++s)
#pragma unroll
            for (int kc = 0; kc < 2; ++kc) {
                bf16x8 af[2], bfr[2];
#pragma unroll
                for (int mt = 0; mt < 2; ++mt)
                    af[mt] = *(const bf16x8*)(As + (s * 128 + wm * 64 + mt * 32 + l32) * 32
                                              + kc * 16 + lh * 8);
#pragma unroll
                for (int nt = 0; nt < 2; ++nt)
                    bfr[nt] = *(const bf16x8*)(Bs + (s * 128 + wn * 64 + nt * 32 + l32) * 32
                                               + kc * 16 + lh * 8);
#pragma unroll
                for (int mt = 0; mt < 2; ++mt)
#pragma unroll
                    for (int nt = 0; nt < 2; ++nt)
                        acc[mt][nt] = __builtin_amdgcn_mfma_f32_32x32x16_bf16(
                            af[mt], bfr[nt], acc[mt][nt], 0, 0, 0);
            }
    }

    // direct stores, full sectors; gelu = 1 transcendental
#pragma unroll
    for (int mt = 0; mt < 2; ++mt)
#pragma unroll
        for (int nt = 0; nt < 2; ++nt) {
            int col = n0 + wn * 64 + nt * 32 + l32;
            int rbase = m0 + wm * 64 + mt * 32 + 4 * lh;
#pragma unroll
            for (int r = 0; r < 16; ++r) {
                int row = rbase + (r & 3) + 8 * (r >> 2);
                C[(size_t)row * 1024 + col] = f2b(gelu_e(acc[mt][nt][r]));
            }
        }
}

// ---------------------------------------------------------------------------
// Fused attention + msg-proj + LayerNorm. One block = 64 Q rows of a window.
// After PV, O round-trips through Ps-overlay (A-layout), multiplies WmT
// (B-frags straight from L2), row-LN in registers, stores bf16 msg to
// source-order rows. O never touches global memory.
// ---------------------------------------------------------------------------
__global__ __launch_bounds__(256)
void attn_msg(const u16* __restrict__ qw, const u16* __restrict__ kw,
              const u16* __restrict__ vt, const u16* __restrict__ wmt,
              const float* __restrict__ g, const float* __restrict__ bb,
              u16* __restrict__ msgb)
{
    __shared__ __align__(16) u16 Ps[64 * 264];

    const int tid = threadIdx.x, w = tid >> 6, lane = tid & 63;
    const int lm = lane & 15, q = lane >> 4;
    const int bid = blockIdx.x;
    const int qc = bid & 3, win = (bid >> 2) & 63, b = bid >> 8;
    const int wi = win >> 3, wj = win & 7;
    const int q0 = qc * 64;
    const size_t wbase = (size_t)(b * 64 + win);
    const u16* kwb = kw + wbase * 256 * 128;
    const u16* qwb = qw + wbase * 256 * 128;
    const u16* vtb = vt + wbase * 128 * 256;

    bf16x8 af[4];
    const u16* qrow = qwb + (size_t)(q0 + w * 16 + lm) * 128;
#pragma unroll
    for (int kt = 0; kt < 4; ++kt)
        af[kt] = *(const bf16x8*)(qrow + kt * 32 + q * 8);

    f32x4 s[16];
#pragma unroll
    for (int nt = 0; nt < 16; ++nt) { f32x4 z = {0.f, 0.f, 0.f, 0.f}; s[nt] = z; }
#pragma unroll
    for (int kt = 0; kt < 4; ++kt)
#pragma unroll
        for (int nt = 0; nt < 16; ++nt) {
            bf16x8 bf = *(const bf16x8*)(kwb + (size_t)(nt * 16 + lm) * 128 + kt * 32 + q * 8);
            s[nt] = __builtin_amdgcn_mfma_f32_16x16x32_bf16(af[kt], bf, s[nt], 0, 0, 0);
        }

    // analytic Swin mask
    int idk[16];
#pragma unroll
    for (int nt = 0; nt < 16; ++nt) {
        int rh = (wi == 7) ? ((nt >= 8) ? 2 : 1) : 0;
        int rw = (wj == 7) ? ((lm >= 8) ? 2 : 1) : 0;
        idk[nt] = rh * 3 + rw;
    }
    const float scale = 0.08838834764831845f;
#pragma unroll
    for (int r = 0; r < 4; ++r) {
        int tq = q0 + w * 16 + q * 4 + r;
        int iq = tq >> 4, jq = tq & 15;
        int rhq = (wi == 7) ? ((iq >= 8) ? 2 : 1) : 0;
        int rwq = (wj == 7) ? ((jq >= 8) ? 2 : 1) : 0;
        int idq = rhq * 3 + rwq;
        float sv[16];
        float mx = -1e30f;
#pragma unroll
        for (int nt = 0; nt < 16; ++nt) {
            float x = s[nt][r] * scale + ((idq != idk[nt]) ? -100.f : 0.f);
            sv[nt] = x; mx = fmaxf(mx, x);
        }
        mx = fmaxf(mx, __shfl_xor(mx, 1));
        mx = fmaxf(mx, __shfl_xor(mx, 2));
        mx = fmaxf(mx, __shfl_xor(mx, 4));
        mx = fmaxf(mx, __shfl_xor(mx, 8));
        float sum = 0.f;
#pragma unroll
        for (int nt = 0; nt < 16; ++nt) { float e = __expf(sv[nt] - mx); sv[nt] = e; sum += e; }
        sum += __shfl_xor(sum, 1);
        sum += __shfl_xor(sum, 2);
        sum += __shfl_xor(sum, 4);
        sum += __shfl_xor(sum, 8);
        float inv = 1.0f / sum;
#pragma unroll
        for (int nt = 0; nt < 16; ++nt)
            Ps[(w * 16 + q * 4 + r) * 264 + nt * 16 + lm] = f2b(sv[nt] * inv);
    }
    __syncthreads();

    // O = P V
    f32x4 o[8];
#pragma unroll
    for (int nt = 0; nt < 8; ++nt) { f32x4 z = {0.f, 0.f, 0.f, 0.f}; o[nt] = z; }
#pragma unroll
    for (int tt = 0; tt < 8; ++tt) {
        bf16x8 pf = *(const bf16x8*)(Ps + (w * 16 + lm) * 264 + tt * 32 + q * 8);
#pragma unroll
        for (int nt = 0; nt < 8; ++nt) {
            bf16x8 vf = *(const bf16x8*)(vtb + (size_t)(nt * 16 + lm) * 256 + tt * 32 + q * 8);
            o[nt] = __builtin_amdgcn_mfma_f32_16x16x32_bf16(pf, vf, o[nt], 0, 0, 0);
        }
    }

    // O -> LDS in MFMA-A layout (overlay on Ps; barrier guards cross-wave overlap)
    __syncthreads();
    u16* Ot = Ps;   // [64][136]
#pragma unroll
    for (int r = 0; r < 4; ++r) {
        int rl = w * 16 + q * 4 + r;
#pragma unroll
        for (int nt = 0; nt < 8; ++nt)
            Ot[rl * 136 + nt * 16 + lm] = f2b(o[nt][r]);
    }
    __syncthreads();

    // msg = O @ WmT^T ; B-frags from global (Wm 32KB, L2-resident)
    f32x4 macc[8];
#pragma unroll
    for (int n2 = 0; n2 < 8; ++n2) { f32x4 z = {0.f, 0.f, 0.f, 0.f}; macc[n2] = z; }
#pragma unroll
    for (int kt = 0; kt < 4; ++kt) {
        bf16x8 paf = *(const bf16x8*)(Ot + (w * 16 + lm) * 136 + kt * 32 + q * 8);
#pragma unroll
        for (int n2 = 0; n2 < 8; ++n2) {
            bf16x8 wf = *(const bf16x8*)(wmt + (size_t)(n2 * 16 + lm) * 128 + kt * 32 + q * 8);
            macc[n2] = __builtin_amdgcn_mfma_f32_16x16x32_bf16(paf, wf, macc[n2], 0, 0, 0);
        }
    }

    // row LN (each msg row lives entirely in one wave: cols n2*16+lm) + store
    float gv[8], bv[8];
#pragma unroll
    for (int n2 = 0; n2 < 8; ++n2) {
        int col = n2 * 16 + lm;
        gv[n2] = g[col]; bv[n2] = bb[col];
    }
#pragma unroll
    for (int r = 0; r < 4; ++r) {
        float s1 = 0.f, s2 = 0.f;
#pragma unroll
        for (int n2 = 0; n2 < 8; ++n2) {
            float v = macc[n2][r];
            s1 += v; s2 += v * v;
        }
        s1 += __shfl_xor(s1, 1); s2 += __shfl_xor(s2, 1);
        s1 += __shfl_xor(s1, 2); s2 += __shfl_xor(s2, 2);
        s1 += __shfl_xor(s1, 4); s2 += __shfl_xor(s2, 4);
        s1 += __shfl_xor(s1, 8); s2 += __shfl_xor(s2, 8);
        float mean = s1 * (1.f / 128.f);
        float var = fmaxf(s2 * (1.f / 128.f) - mean * mean, 0.f);
        float rs = rsqrtf(var + 1e-5f);
        int t = q0 + w * 16 + q * 4 + r;
        int ii = t >> 4, jj = t & 15;
        int h = (wi * 16 + ii + 8) & 127;
        int w2 = (wj * 16 + jj + 8) & 127;
        size_t orow = ((size_t)b * 16384 + h * 128 + w2) * 128;
#pragma unroll
        for (int n2 = 0; n2 < 8; ++n2)
            msgb[orow + n2 * 16 + lm] = f2b((macc[n2][r] - mean) * rs * gv[n2] + bv[n2]);
    }
}

// ---------------------------------------------------------------------------
// FFN2 + LN + residual. BM=64, BK=128 streaming over K=1024. LN stats in
// registers + 1KB LDS exchange. fp32 out = resid + LN (full-sector stores).
// ---------------------------------------------------------------------------
__global__ __launch_bounds__(256, 3)
void gemm_ffn2(const u16* __restrict__ A, const u16* __restrict__ Bt,
               const float* __restrict__ g, const float* __restrict__ bb,
               const float* __restrict__ resid, float* __restrict__ outv)
{
    __shared__ __align__(16) u16 SMEM[25088];
    u16* As = SMEM;                         // [4][64][32]
    u16* Bs = SMEM + 8192;                  // [4][128][32]
    float* stats = (float*)(SMEM + 24576);  // [64][4]

    const int tid = threadIdx.x;
    const int w = tid >> 6, lane = tid & 63;
    const int lm = lane & 15, q = lane >> 4;
    const int wm = w >> 1, wn = w & 1;
    const int m0 = blockIdx.x * 64;
    const int K = 1024;

    f32x4 acc[2][4] = {};
#pragma unroll
    for (int kt2 = 0; kt2 < 8; ++kt2) {
        __syncthreads();
#pragma unroll
        for (int s = 0; s < 4; ++s) {
            int kc = kt2 * 128 + s * 32 + (lane & 3) * 8;
            int arow = w * 16 + (lane >> 2);
            cp16(A + (size_t)(m0 + arow) * K + kc,
                 (void*)(As + (s * 64 + w * 16) * 32));
#pragma unroll
            for (int i = 0; i < 2; ++i) {
                int brow = w * 32 + i * 16 + (lane >> 2);
                cp16(Bt + (size_t)brow * K + kc,
                     (void*)(Bs + (s * 128 + w * 32 + i * 16) * 32));
            }
        }
        __syncthreads();
#pragma unroll
        for (int s = 0; s < 4; ++s) {
            bf16x8 af[2], bfr[4];
#pragma unroll
            for (int t = 0; t < 2; ++t)
                af[t] = *(const bf16x8*)(As + (s * 64 + wm * 32 + t * 16 + lm) * 32 + q * 8);
#pragma unroll
            for (int t = 0; t < 4; ++t)
                bfr[t] = *(const bf16x8*)(Bs + (s * 128 + wn * 64 + t * 16 + lm) * 32 + q * 8);
#pragma unroll
            for (int mt = 0; mt < 2; ++mt)
#pragma unroll
                for (int nt = 0; nt < 4; ++nt)
                    acc[mt][nt] = __builtin_amdgcn_mfma_f32_16x16x32_bf16(
                        af[mt], bfr[nt], acc[mt][nt], 0, 0, 0);
        }
    }

#pragma unroll
    for (int mt = 0; mt < 2; ++mt)
#pragma unroll
        for (int r = 0; r < 4; ++r) {
            float s1 = 0.f, s2 = 0.f;
#pragma unroll
            for (int nt = 0; nt < 4; ++nt) {
                float v = acc[mt][nt][r];
                s1 += v; s2 += v * v;
            }
            s1 += __shfl_xor(s1, 1); s2 += __shfl_xor(s2, 1);
            s1 += __shfl_xor(s1, 2); s2 += __shfl_xor(s2, 2);
            s1 += __shfl_xor(s1, 4); s2 += __shfl_xor(s2, 4);
            s1 += __shfl_xor(s1, 8); s2 += __shfl_xor(s2, 8);
            if (lm == 0) {
                int row = wm * 32 + mt * 16 + q * 4 + r;
                stats[row * 4 + wn * 2] = s1;
                stats[row * 4 + wn * 2 + 1] = s2;
            }
        }
    __syncthreads();

    float gv[4], bv[4];
#pragma unroll
    for (int nt = 0; nt < 4; ++nt) {
        int col = wn * 64 + nt * 16 + lm;
        gv[nt] = g[col]; bv[nt] = bb[col];
    }
#pragma unroll
    for (int mt = 0; mt < 2; ++mt)
#pragma unroll
        for (int r = 0; r < 4; ++r) {
            int row = wm * 32 + mt * 16 + q * 4 + r;
            f32x4 st = *(const f32x4*)(stats + row * 4);
            float mean = (st[0] + st[2]) * (1.f / 128.f);
            float var = fmaxf((st[1] + st[3]) * (1.f / 128.f) - mean * mean, 0.f);
            float rs = rsqrtf(var + 1e-5f);
#pragma unroll
            for (int nt = 0; nt < 4; ++nt) {
                int col = wn * 64 + nt * 16 + lm;
                size_t gi = (size_t)(m0 + row) * 128 + col;
                outv[gi] = (acc[mt][nt][r] - mean) * rs * gv[nt] + bv[nt] + resid[gi];
            }
        }
}

// ---------------------------------------------------------------------------
// Prep (merged): weight transposes WRITE-coalesced (consecutive lanes ->
// consecutive k of the output; strided reads absorbed by L1/L2), plus
// fp32->bf16 activation cast.
// ---------------------------------------------------------------------------
__global__ void prep_all(const float* __restrict__ Wq, const float* __restrict__ Wk,
                         const float* __restrict__ Wv, const float* __restrict__ Wm,
                         const float* __restrict__ W1, const float* __restrict__ W2,
                         const float* __restrict__ src, const float* __restrict__ tgt,
                         u16* __restrict__ ws, u16* __restrict__ srcb,
                         u16* __restrict__ tgtb)
{
    int bx = blockIdx.x;
    if (bx < 1792) {
        int idx = bx * 256 + threadIdx.x;
        if (idx < 65536) {                       // Wq,Wk,Wv,Wm: 128x128
            int m = idx >> 14, e = idx & 16383;
            const float* sp = (m == 0) ? Wq : (m == 1) ? Wk : (m == 2) ? Wv : Wm;
            int n = e >> 7, k = e & 127;
            ws[m * 16384 + n * 128 + k] = f2b(sp[k * 128 + n]);
        } else if (idx < 327680) {               // W1 (256,1024) -> (1024,256)
            int e = idx - 65536;
            int n = e >> 8, k = e & 255;
            ws[65536 + n * 256 + k] = f2b(W1[k * 1024 + n]);
        } else {                                  // W2 (1024,128) -> (128,1024)
            int e = idx - 327680;
            int n = e >> 10, k = e & 1023;
            ws[327680 + n * 1024 + k] = f2b(W2[k * 128 + n]);
        }
    } else {
        int idx = (bx - 1792) * 256 + threadIdx.x;   // 0..2097151
        const float* s; u16* d; int i;
        if (idx < 1048576) { s = src; d = srcb; i = idx * 4; }
        else               { s = tgt; d = tgtb; i = (idx - 1048576) * 4; }
        f32x4 v = *(const f32x4*)(s + i);
        u16x4 o; o[0] = f2b(v[0]); o[1] = f2b(v[1]); o[2] = f2b(v[2]); o[3] = f2b(v[3]);
        *(u16x4*)(d + i) = o;
    }
}

// ---------------------------------------------------------------------------
// Workspace layout (u16 element offsets)
// ---------------------------------------------------------------------------
#define OFF_WQT  0u            // concat [WqT;WkT;WvT] 3x(128x128)
#define OFF_WMT  49152u
#define OFF_W1T  65536u
#define OFF_W2T  327680u
#define OFF_SRCB 458752u
#define OFF_TGTB 4653056u
#define OFF_QW   8847360u
#define OFF_KW   13041664u
#define OFF_VWT  17235968u
#define OFF_MSGB 21430272u     // bf16 msg, source-order (was ATTN region)
#define OFF_HID  25624576u     // bf16 32768x1024, ends 59179008

extern "C" void kernel_launch(void* const* d_in, const int* in_sizes, int n_in,
                              void* d_out, int out_size, void* d_ws, size_t ws_size,
                              hipStream_t stream)
{
    (void)in_sizes; (void)n_in; (void)out_size; (void)ws_size;
    const float* source = (const float*)d_in[0];
    const float* target = (const float*)d_in[1];
    const float* Wq = (const float*)d_in[2];
    const float* Wk = (const float*)d_in[3];
    const float* Wv = (const float*)d_in[4];
    const float* Wm = (const float*)d_in[5];
    const float* g1 = (const float*)d_in[6];
    const float* b1 = (const float*)d_in[7];
    const float* W1 = (const float*)d_in[8];
    const float* W2 = (const float*)d_in[9];
    const float* g2 = (const float*)d_in[10];
    const float* b2 = (const float*)d_in[11];
    u16* ws = (u16*)d_ws;
    float* out = (float*)d_out;

    prep_all<<<9984, 256, 0, stream>>>(Wq, Wk, Wv, Wm, W1, W2, source, target,
                                       ws, ws + OFF_SRCB, ws + OFF_TGTB);
    gemm_qkv<<<dim3(256, 3), 256, 0, stream>>>(
        ws + OFF_SRCB, ws + OFF_TGTB, ws + OFF_WQT,
        ws + OFF_QW, ws + OFF_KW, ws + OFF_VWT);
    // attention + msg-proj + LN fused -> bf16 msg in source order
    attn_msg<<<512, 256, 0, stream>>>(
        ws + OFF_QW, ws + OFF_KW, ws + OFF_VWT, ws + OFF_WMT, g1, b1,
        ws + OFF_MSGB);
    // ffn1: gelu(cat(src,msg) @ W1) -> bf16 HID
    gemm_ffn1<<<dim3(256, 8), 256, 0, stream>>>(
        ws + OFF_SRCB, ws + OFF_MSGB, ws + OFF_W1T, ws + OFF_HID);
    // ffn2 + LN + residual -> fp32 out
    gemm_ffn2<<<512, 256, 0, stream>>>(
        ws + OFF_HID, ws + OFF_W2T, g2, b2, source, out);
}

// Round 7
// 207.776 us; speedup vs baseline: 1.7074x; 1.1188x over previous
//
#include <hip/hip_runtime.h>
#include <math.h>
#include <stdint.h>

// ---------------------------------------------------------------------------
// TransformerLayer (Swin-style) on MI355X. FP32 I/O; bf16 MFMA internals.
// B=2, H=W=128, C=128, NS=8 -> 64 windows x 256 tokens; HID=1024.
// R7: attn_msg rebuilt with cp16 LDS staging for Q/K/V/Wm (R6 was latency-
//     bound: MfmaUtil 4%, per-MFMA 16B global frag loads). 32KB staging
//     buffer cycles K0/K1/V0/V1/Wm; V0 load overlapped with softmax.
// ---------------------------------------------------------------------------

typedef unsigned short u16;
typedef __attribute__((ext_vector_type(8))) short bf16x8;   // 8 bf16 (4 VGPRs)
typedef __attribute__((ext_vector_type(4))) float f32x4;
typedef __attribute__((ext_vector_type(16))) float f32x16;  // 32x32 accumulator
typedef __attribute__((ext_vector_type(4))) short u16x4;

__device__ __forceinline__ u16 f2b(float f) {
    unsigned int i = __float_as_uint(f);
    unsigned int r = (i + 0x7fffu + ((i >> 16) & 1u)) >> 16;
    return (u16)r;
}

// gelu via A-S 7.1.28 erf (|eps|<=5e-4): ONE transcendental (rcp).
__device__ __forceinline__ float gelu_e(float x) {
    float y = fabsf(x) * 0.70710678118f;
    float u = fmaf(y, fmaf(y, fmaf(y, fmaf(y, 0.078108f, 0.000972f),
                                   0.230389f), 0.278393f), 1.0f);
    u = u * u; u = u * u;
    float r = __builtin_amdgcn_rcpf(u);
    return fmaxf(x, 0.f) - 0.5f * fabsf(x) * r;
}

// 16B async global->LDS (m97-verified). LDS dest wave-uniform base + lane*16.
__device__ __forceinline__ void cp16(const void* g, void* l) {
    auto* gp = reinterpret_cast<const __attribute__((address_space(1))) unsigned int*>(
        reinterpret_cast<uintptr_t>(g));
    auto* lp = reinterpret_cast<__attribute__((address_space(3))) unsigned int*>(
        reinterpret_cast<uintptr_t>(l));
    __builtin_amdgcn_global_load_lds(gp, lp, 16, 0, 0);
}

// window row (b*16384 + win*256 + t) -> source-order row (b*16384 + h*128 + w)
__device__ __forceinline__ int win_map(int gm) {
    int b = gm >> 14, rr = gm & 16383;
    int win = rr >> 8, t = rr & 255;
    int wi = win >> 3, wj = win & 7, i = t >> 4, j = t & 15;
    int h = (wi * 16 + i + 8) & 127;
    int w = (wj * 16 + j + 8) & 127;
    return (b << 14) + h * 128 + w;
}

// ---------------------------------------------------------------------------
// Fused QKV: grid (256, 3). y=0: q=src@Wq, y=1: k=tgt@Wk (window layouts),
// y=2: v=tgt@Wv stored transposed per window. K=128 fully LDS-resident.
// ---------------------------------------------------------------------------
__global__ __launch_bounds__(256, 2)
void gemm_qkv(const u16* __restrict__ srcb, const u16* __restrict__ tgtb,
              const u16* __restrict__ Bt, u16* __restrict__ qw,
              u16* __restrict__ kw, u16* __restrict__ vwt)
{
    __shared__ __align__(16) u16 SMEM[32768];   // As[4][128][32] | Bs[4][128][32]
    u16* As = SMEM;
    u16* Bs = SMEM + 16384;
    u16* Ts = SMEM;                              // 128x136 epilogue overlay

    const int tid = threadIdx.x;
    const int w = tid >> 6, lane = tid & 63;
    const int lm = lane & 15, q = lane >> 4;
    const int wm = w >> 1, wn = w & 1;
    const int m0 = blockIdx.x * 128;
    const int y = blockIdx.y;
    const u16* Ab = (y == 0) ? srcb : tgtb;

#pragma unroll
    for (int s = 0; s < 4; ++s)
#pragma unroll
        for (int i = 0; i < 2; ++i) {
            int row = w * 32 + i * 16 + (lane >> 2);
            int kc = s * 32 + (lane & 3) * 8;
            cp16(Ab + (size_t)win_map(m0 + row) * 128 + kc,
                 (void*)(As + (s * 128 + w * 32 + i * 16) * 32));
            cp16(Bt + (size_t)(y * 128 + row) * 128 + kc,
                 (void*)(Bs + (s * 128 + w * 32 + i * 16) * 32));
        }
    __syncthreads();

    f32x4 acc[4][4] = {};
#pragma unroll
    for (int s = 0; s < 4; ++s) {
        bf16x8 af[4], bfr[4];
#pragma unroll
        for (int t = 0; t < 4; ++t)
            af[t] = *(const bf16x8*)(As + (s * 128 + wm * 64 + t * 16 + lm) * 32 + q * 8);
#pragma unroll
        for (int t = 0; t < 4; ++t)
            bfr[t] = *(const bf16x8*)(Bs + (s * 128 + wn * 64 + t * 16 + lm) * 32 + q * 8);
#pragma unroll
        for (int mt = 0; mt < 4; ++mt)
#pragma unroll
            for (int nt = 0; nt < 4; ++nt)
                acc[mt][nt] = __builtin_amdgcn_mfma_f32_16x16x32_bf16(
                    af[mt], bfr[nt], acc[mt][nt], 0, 0, 0);
    }

    __syncthreads();
#pragma unroll
    for (int mt = 0; mt < 4; ++mt)
#pragma unroll
        for (int nt = 0; nt < 4; ++nt)
#pragma unroll
            for (int r = 0; r < 4; ++r) {
                int rowl = wm * 64 + mt * 16 + q * 4 + r;
                int col = wn * 64 + nt * 16 + lm;
                int idx = (y == 2) ? col * 136 + rowl : rowl * 136 + col;
                Ts[idx] = f2b(acc[mt][nt][r]);
            }
    __syncthreads();
    const int c8 = (tid & 15) * 8;
#pragma unroll
    for (int i = 0; i < 8; ++i) {
        int rr = i * 16 + (tid >> 4);
        bf16x8 t = *(const bf16x8*)(Ts + rr * 136 + c8);
        if (y == 2) {
            int wix = m0 >> 8, tok0 = m0 & 255;   // vwT[(b*64+win)*128+ch][tok]
            *(bf16x8*)(vwt + (size_t)wix * 32768 + (size_t)rr * 256 + tok0 + c8) = t;
        } else {
            u16* Cv = (y == 0) ? qw : kw;
            *(bf16x8*)(Cv + (size_t)(m0 + rr) * 128 + c8) = t;
        }
    }
}

// ---------------------------------------------------------------------------
// FFN1: gelu(concat(src,msg) @ W1) -> bf16 HID. 32x32x16 MFMA, BM=BN=BK=128.
// Direct full-sector bf16 stores; 1-transcendental gelu.
// ---------------------------------------------------------------------------
__global__ __launch_bounds__(256, 2)
void gemm_ffn1(const u16* __restrict__ A0, const u16* __restrict__ A1,
               const u16* __restrict__ Bt, u16* __restrict__ C)
{
    __shared__ __align__(16) u16 SMEM[32768];
    u16* As = SMEM;
    u16* Bs = SMEM + 16384;

    const int tid = threadIdx.x;
    const int w = tid >> 6, lane = tid & 63;
    const int l32 = lane & 31, lh = lane >> 5;
    const int wm = w >> 1, wn = w & 1;
    const int m0 = blockIdx.x * 128, n0 = blockIdx.y * 128;

    f32x16 acc[2][2] = {};
#pragma unroll
    for (int kt2 = 0; kt2 < 2; ++kt2) {
        __syncthreads();
        const u16* Ab = kt2 ? A1 : A0;   // cat(src, msg): K halves
#pragma unroll
        for (int s = 0; s < 4; ++s)
#pragma unroll
            for (int i = 0; i < 2; ++i) {
                int row = w * 32 + i * 16 + (lane >> 2);
                int kc = s * 32 + (lane & 3) * 8;
                cp16(Ab + (size_t)(m0 + row) * 128 + kc,
                     (void*)(As + (s * 128 + w * 32 + i * 16) * 32));
                cp16(Bt + (size_t)(n0 + row) * 256 + kt2 * 128 + kc,
                     (void*)(Bs + (s * 128 + w * 32 + i * 16) * 32));
            }
        __syncthreads();
#pragma unroll
        for (int s = 0; s < 4; ++s)
#pragma unroll
            for (int kc = 0; kc < 2; ++kc) {
                bf16x8 af[2], bfr[2];
#pragma unroll
                for (int mt = 0; mt < 2; ++mt)
                    af[mt] = *(const bf16x8*)(As + (s * 128 + wm * 64 + mt * 32 + l32) * 32
                                              + kc * 16 + lh * 8);
#pragma unroll
                for (int nt = 0; nt < 2; ++nt)
                    bfr[nt] = *(const bf16x8*)(Bs + (s * 128 + wn * 64 + nt * 32 + l32) * 32
                                               + kc * 16 + lh * 8);
#pragma unroll
                for (int mt = 0; mt < 2; ++mt)
#pragma unroll
                    for (int nt = 0; nt < 2; ++nt)
                        acc[mt][nt] = __builtin_amdgcn_mfma_f32_32x32x16_bf16(
                            af[mt], bfr[nt], acc[mt][nt], 0, 0, 0);
            }
    }

#pragma unroll
    for (int mt = 0; mt < 2; ++mt)
#pragma unroll
        for (int nt = 0; nt < 2; ++nt) {
            int col = n0 + wn * 64 + nt * 32 + l32;
            int rbase = m0 + wm * 64 + mt * 32 + 4 * lh;
#pragma unroll
            for (int r = 0; r < 16; ++r) {
                int row = rbase + (r & 3) + 8 * (r >> 2);
                C[(size_t)row * 1024 + col] = f2b(gelu_e(acc[mt][nt][r]));
            }
        }
}

// ---------------------------------------------------------------------------
// Fused attention + msg-proj + LayerNorm, fully LDS-staged operands.
// One block = 64 Q rows of a window; grid 512. LDS: Ps 33.8KB + B32 32KB.
// B32 cycles: K-tok[0,128) -> K-tok[128,256) -> V-tok[0,128) -> V-tok[128,256)
// -> WmT. Q staged in Ps overlay. All MFMA operands come from LDS.
// ---------------------------------------------------------------------------
__global__ __launch_bounds__(256, 2)
void attn_msg(const u16* __restrict__ qw, const u16* __restrict__ kw,
              const u16* __restrict__ vt, const u16* __restrict__ wmt,
              const float* __restrict__ g, const float* __restrict__ bb,
              u16* __restrict__ msgb)
{
    __shared__ __align__(16) u16 Ps[64 * 264];   // P (stride 264); Q/Ot overlays
    __shared__ __align__(16) u16 B32[16384];     // 32KB staging buffer

    const int tid = threadIdx.x, w = tid >> 6, lane = tid & 63;
    const int lm = lane & 15, q = lane >> 4;
    const int l4r = lane >> 2, l4c = (lane & 3) * 8;
    const int bid = blockIdx.x;
    const int qc = bid & 3, win = (bid >> 2) & 63, b = bid >> 8;
    const int wi = win >> 3, wj = win & 7;
    const int q0 = qc * 64;
    const size_t wbase = (size_t)(b * 64 + win);
    const u16* kwb = kw + wbase * 256 * 128;
    const u16* qwb = qw + wbase * 256 * 128;
    const u16* vtb = vt + wbase * 128 * 256;

    // ---- stage Q (Ps overlay, [4 kt][64 row][32]) + K tok[0,128) ----
    u16* Qs = Ps;
#pragma unroll
    for (int i = 0; i < 4; ++i)
        cp16(qwb + (size_t)(q0 + w * 16 + l4r) * 128 + i * 32 + l4c,
             (void*)(Qs + (i * 64 + w * 16) * 32));
#pragma unroll
    for (int s = 0; s < 4; ++s)
#pragma unroll
        for (int i = 0; i < 2; ++i) {
            int tok = w * 32 + i * 16 + l4r;
            cp16(kwb + (size_t)tok * 128 + s * 32 + l4c,
                 (void*)(B32 + (s * 128 + w * 32 + i * 16) * 32));
        }
    __syncthreads();

    bf16x8 af[4];
#pragma unroll
    for (int kt = 0; kt < 4; ++kt)
        af[kt] = *(const bf16x8*)(Qs + (kt * 64 + w * 16 + lm) * 32 + q * 8);

    f32x4 s[16];
#pragma unroll
    for (int nt = 0; nt < 16; ++nt) { f32x4 z = {0.f, 0.f, 0.f, 0.f}; s[nt] = z; }
#pragma unroll
    for (int kt = 0; kt < 4; ++kt)
#pragma unroll
        for (int nt = 0; nt < 8; ++nt) {
            bf16x8 bf = *(const bf16x8*)(B32 + (kt * 128 + nt * 16 + lm) * 32 + q * 8);
            s[nt] = __builtin_amdgcn_mfma_f32_16x16x32_bf16(af[kt], bf, s[nt], 0, 0, 0);
        }
    __syncthreads();
    // ---- K tok[128,256) ----
#pragma unroll
    for (int ss = 0; ss < 4; ++ss)
#pragma unroll
        for (int i = 0; i < 2; ++i) {
            int tok = 128 + w * 32 + i * 16 + l4r;
            cp16(kwb + (size_t)tok * 128 + ss * 32 + l4c,
                 (void*)(B32 + (ss * 128 + w * 32 + i * 16) * 32));
        }
    __syncthreads();
#pragma unroll
    for (int kt = 0; kt < 4; ++kt)
#pragma unroll
        for (int nt = 8; nt < 16; ++nt) {
            bf16x8 bf = *(const bf16x8*)(B32 + (kt * 128 + (nt - 8) * 16 + lm) * 32 + q * 8);
            s[nt] = __builtin_amdgcn_mfma_f32_16x16x32_bf16(af[kt], bf, s[nt], 0, 0, 0);
        }
    __syncthreads();   // B32 reads done -> free for V

    // ---- issue V tok[0,128) load, then softmax (overlap) ----
#pragma unroll
    for (int tt = 0; tt < 4; ++tt)
#pragma unroll
        for (int i = 0; i < 2; ++i) {
            int ch = w * 32 + i * 16 + l4r;
            cp16(vtb + (size_t)ch * 256 + tt * 32 + l4c,
                 (void*)(B32 + (tt * 128 + w * 32 + i * 16) * 32));
        }

    // analytic Swin mask + softmax (regs), P -> Ps
    int idk[16];
#pragma unroll
    for (int nt = 0; nt < 16; ++nt) {
        int rh = (wi == 7) ? ((nt >= 8) ? 2 : 1) : 0;
        int rw = (wj == 7) ? ((lm >= 8) ? 2 : 1) : 0;
        idk[nt] = rh * 3 + rw;
    }
    const float scale = 0.08838834764831845f;
#pragma unroll
    for (int r = 0; r < 4; ++r) {
        int tq = q0 + w * 16 + q * 4 + r;
        int iq = tq >> 4, jq = tq & 15;
        int rhq = (wi == 7) ? ((iq >= 8) ? 2 : 1) : 0;
        int rwq = (wj == 7) ? ((jq >= 8) ? 2 : 1) : 0;
        int idq = rhq * 3 + rwq;
        float sv[16];
        float mx = -1e30f;
#pragma unroll
        for (int nt = 0; nt < 16; ++nt) {
            float x = s[nt][r] * scale + ((idq != idk[nt]) ? -100.f : 0.f);
            sv[nt] = x; mx = fmaxf(mx, x);
        }
        mx = fmaxf(mx, __shfl_xor(mx, 1));
        mx = fmaxf(mx, __shfl_xor(mx, 2));
        mx = fmaxf(mx, __shfl_xor(mx, 4));
        mx = fmaxf(mx, __shfl_xor(mx, 8));
        float sum = 0.f;
#pragma unroll
        for (int nt = 0; nt < 16; ++nt) { float e = __expf(sv[nt] - mx); sv[nt] = e; sum += e; }
        sum += __shfl_xor(sum, 1);
        sum += __shfl_xor(sum, 2);
        sum += __shfl_xor(sum, 4);
        sum += __shfl_xor(sum, 8);
        float inv = 1.0f / sum;
#pragma unroll
        for (int nt = 0; nt < 16; ++nt)
            Ps[(w * 16 + q * 4 + r) * 264 + nt * 16 + lm] = f2b(sv[nt] * inv);
    }
    __syncthreads();   // V0 loaded (barrier drains vmcnt) + P visible

    // ---- PV tok[0,128) ----
    f32x4 o[8];
#pragma unroll
    for (int nt = 0; nt < 8; ++nt) { f32x4 z = {0.f, 0.f, 0.f, 0.f}; o[nt] = z; }
#pragma unroll
    for (int tt = 0; tt < 4; ++tt) {
        bf16x8 pf = *(const bf16x8*)(Ps + (w * 16 + lm) * 264 + tt * 32 + q * 8);
#pragma unroll
        for (int nt = 0; nt < 8; ++nt) {
            bf16x8 vf = *(const bf16x8*)(B32 + (tt * 128 + nt * 16 + lm) * 32 + q * 8);
            o[nt] = __builtin_amdgcn_mfma_f32_16x16x32_bf16(pf, vf, o[nt], 0, 0, 0);
        }
    }
    __syncthreads();
    // ---- V tok[128,256) ----
#pragma unroll
    for (int tt = 0; tt < 4; ++tt)
#pragma unroll
        for (int i = 0; i < 2; ++i) {
            int ch = w * 32 + i * 16 + l4r;
            cp16(vtb + (size_t)ch * 256 + 128 + tt * 32 + l4c,
                 (void*)(B32 + (tt * 128 + w * 32 + i * 16) * 32));
        }
    __syncthreads();
#pragma unroll
    for (int tt = 4; tt < 8; ++tt) {
        bf16x8 pf = *(const bf16x8*)(Ps + (w * 16 + lm) * 264 + tt * 32 + q * 8);
#pragma unroll
        for (int nt = 0; nt < 8; ++nt) {
            bf16x8 vf = *(const bf16x8*)(B32 + ((tt - 4) * 128 + nt * 16 + lm) * 32 + q * 8);
            o[nt] = __builtin_amdgcn_mfma_f32_16x16x32_bf16(pf, vf, o[nt], 0, 0, 0);
        }
    }
    __syncthreads();   // V reads + P reads done

    // ---- issue Wm stage; write O -> Ot (Ps overlay, A-layout) ----
#pragma unroll
    for (int ss = 0; ss < 4; ++ss)
#pragma unroll
        for (int i = 0; i < 2; ++i) {
            int n = w * 32 + i * 16 + l4r;
            cp16(wmt + (size_t)n * 128 + ss * 32 + l4c,
                 (void*)(B32 + (ss * 128 + w * 32 + i * 16) * 32));
        }
    u16* Ot = Ps;   // [64][136]
#pragma unroll
    for (int r = 0; r < 4; ++r) {
        int rl = w * 16 + q * 4 + r;
#pragma unroll
        for (int nt = 0; nt < 8; ++nt)
            Ot[rl * 136 + nt * 16 + lm] = f2b(o[nt][r]);
    }
    __syncthreads();

    // ---- msg = O @ WmT^T (all-LDS) ----
    f32x4 macc[8];
#pragma unroll
    for (int n2 = 0; n2 < 8; ++n2) { f32x4 z = {0.f, 0.f, 0.f, 0.f}; macc[n2] = z; }
#pragma unroll
    for (int kt = 0; kt < 4; ++kt) {
        bf16x8 paf = *(const bf16x8*)(Ot + (w * 16 + lm) * 136 + kt * 32 + q * 8);
#pragma unroll
        for (int n2 = 0; n2 < 8; ++n2) {
            bf16x8 wf = *(const bf16x8*)(B32 + (kt * 128 + n2 * 16 + lm) * 32 + q * 8);
            macc[n2] = __builtin_amdgcn_mfma_f32_16x16x32_bf16(paf, wf, macc[n2], 0, 0, 0);
        }
    }

    // ---- row LN + store (source-order rows) ----
    float gv[8], bv[8];
#pragma unroll
    for (int n2 = 0; n2 < 8; ++n2) {
        int col = n2 * 16 + lm;
        gv[n2] = g[col]; bv[n2] = bb[col];
    }
#pragma unroll
    for (int r = 0; r < 4; ++r) {
        float s1 = 0.f, s2 = 0.f;
#pragma unroll
        for (int n2 = 0; n2 < 8; ++n2) {
            float v = macc[n2][r];
            s1 += v; s2 += v * v;
        }
        s1 += __shfl_xor(s1, 1); s2 += __shfl_xor(s2, 1);
        s1 += __shfl_xor(s1, 2); s2 += __shfl_xor(s2, 2);
        s1 += __shfl_xor(s1, 4); s2 += __shfl_xor(s2, 4);
        s1 += __shfl_xor(s1, 8); s2 += __shfl_xor(s2, 8);
        float mean = s1 * (1.f / 128.f);
        float var = fmaxf(s2 * (1.f / 128.f) - mean * mean, 0.f);
        float rs = rsqrtf(var + 1e-5f);
        int t = q0 + w * 16 + q * 4 + r;
        int ii = t >> 4, jj = t & 15;
        int h = (wi * 16 + ii + 8) & 127;
        int w2 = (wj * 16 + jj + 8) & 127;
        size_t orow = ((size_t)b * 16384 + h * 128 + w2) * 128;
#pragma unroll
        for (int n2 = 0; n2 < 8; ++n2)
            msgb[orow + n2 * 16 + lm] = f2b((macc[n2][r] - mean) * rs * gv[n2] + bv[n2]);
    }
}

// ---------------------------------------------------------------------------
// FFN2 + LN + residual. BM=64, BK=128 streaming over K=1024. LN stats in
// registers + 1KB LDS exchange. fp32 out = resid + LN (full-sector stores).
// ---------------------------------------------------------------------------
__global__ __launch_bounds__(256, 3)
void gemm_ffn2(const u16* __restrict__ A, const u16* __restrict__ Bt,
               const float* __restrict__ g, const float* __restrict__ bb,
               const float* __restrict__ resid, float* __restrict__ outv)
{
    __shared__ __align__(16) u16 SMEM[25088];
    u16* As = SMEM;                         // [4][64][32]
    u16* Bs = SMEM + 8192;                  // [4][128][32]
    float* stats = (float*)(SMEM + 24576);  // [64][4]

    const int tid = threadIdx.x;
    const int w = tid >> 6, lane = tid & 63;
    const int lm = lane & 15, q = lane >> 4;
    const int wm = w >> 1, wn = w & 1;
    const int m0 = blockIdx.x * 64;
    const int K = 1024;

    f32x4 acc[2][4] = {};
#pragma unroll
    for (int kt2 = 0; kt2 < 8; ++kt2) {
        __syncthreads();
#pragma unroll
        for (int s = 0; s < 4; ++s) {
            int kc = kt2 * 128 + s * 32 + (lane & 3) * 8;
            int arow = w * 16 + (lane >> 2);
            cp16(A + (size_t)(m0 + arow) * K + kc,
                 (void*)(As + (s * 64 + w * 16) * 32));
#pragma unroll
            for (int i = 0; i < 2; ++i) {
                int brow = w * 32 + i * 16 + (lane >> 2);
                cp16(Bt + (size_t)brow * K + kc,
                     (void*)(Bs + (s * 128 + w * 32 + i * 16) * 32));
            }
        }
        __syncthreads();
#pragma unroll
        for (int s = 0; s < 4; ++s) {
            bf16x8 af[2], bfr[4];
#pragma unroll
            for (int t = 0; t < 2; ++t)
                af[t] = *(const bf16x8*)(As + (s * 64 + wm * 32 + t * 16 + lm) * 32 + q * 8);
#pragma unroll
            for (int t = 0; t < 4; ++t)
                bfr[t] = *(const bf16x8*)(Bs + (s * 128 + wn * 64 + t * 16 + lm) * 32 + q * 8);
#pragma unroll
            for (int mt = 0; mt < 2; ++mt)
#pragma unroll
                for (int nt = 0; nt < 4; ++nt)
                    acc[mt][nt] = __builtin_amdgcn_mfma_f32_16x16x32_bf16(
                        af[mt], bfr[nt], acc[mt][nt], 0, 0, 0);
        }
    }

#pragma unroll
    for (int mt = 0; mt < 2; ++mt)
#pragma unroll
        for (int r = 0; r < 4; ++r) {
            float s1 = 0.f, s2 = 0.f;
#pragma unroll
            for (int nt = 0; nt < 4; ++nt) {
                float v = acc[mt][nt][r];
                s1 += v; s2 += v * v;
            }
            s1 += __shfl_xor(s1, 1); s2 += __shfl_xor(s2, 1);
            s1 += __shfl_xor(s1, 2); s2 += __shfl_xor(s2, 2);
            s1 += __shfl_xor(s1, 4); s2 += __shfl_xor(s2, 4);
            s1 += __shfl_xor(s1, 8); s2 += __shfl_xor(s2, 8);
            if (lm == 0) {
                int row = wm * 32 + mt * 16 + q * 4 + r;
                stats[row * 4 + wn * 2] = s1;
                stats[row * 4 + wn * 2 + 1] = s2;
            }
        }
    __syncthreads();

    float gv[4], bv[4];
#pragma unroll
    for (int nt = 0; nt < 4; ++nt) {
        int col = wn * 64 + nt * 16 + lm;
        gv[nt] = g[col]; bv[nt] = bb[col];
    }
#pragma unroll
    for (int mt = 0; mt < 2; ++mt)
#pragma unroll
        for (int r = 0; r < 4; ++r) {
            int row = wm * 32 + mt * 16 + q * 4 + r;
            f32x4 st = *(const f32x4*)(stats + row * 4);
            float mean = (st[0] + st[2]) * (1.f / 128.f);
            float var = fmaxf((st[1] + st[3]) * (1.f / 128.f) - mean * mean, 0.f);
            float rs = rsqrtf(var + 1e-5f);
#pragma unroll
            for (int nt = 0; nt < 4; ++nt) {
                int col = wn * 64 + nt * 16 + lm;
                size_t gi = (size_t)(m0 + row) * 128 + col;
                outv[gi] = (acc[mt][nt][r] - mean) * rs * gv[nt] + bv[nt] + resid[gi];
            }
        }
}

// ---------------------------------------------------------------------------
// Prep (merged): weight transposes write-coalesced; fp32->bf16 act cast.
// ---------------------------------------------------------------------------
__global__ void prep_all(const float* __restrict__ Wq, const float* __restrict__ Wk,
                         const float* __restrict__ Wv, const float* __restrict__ Wm,
                         const float* __restrict__ W1, const float* __restrict__ W2,
                         const float* __restrict__ src, const float* __restrict__ tgt,
                         u16* __restrict__ ws, u16* __restrict__ srcb,
                         u16* __restrict__ tgtb)
{
    int bx = blockIdx.x;
    if (bx < 1792) {
        int idx = bx * 256 + threadIdx.x;
        if (idx < 65536) {                       // Wq,Wk,Wv,Wm: 128x128
            int m = idx >> 14, e = idx & 16383;
            const float* sp = (m == 0) ? Wq : (m == 1) ? Wk : (m == 2) ? Wv : Wm;
            int n = e >> 7, k = e & 127;
            ws[m * 16384 + n * 128 + k] = f2b(sp[k * 128 + n]);
        } else if (idx < 327680) {               // W1 (256,1024) -> (1024,256)
            int e = idx - 65536;
            int n = e >> 8, k = e & 255;
            ws[65536 + n * 256 + k] = f2b(W1[k * 1024 + n]);
        } else {                                  // W2 (1024,128) -> (128,1024)
            int e = idx - 327680;
            int n = e >> 10, k = e & 1023;
            ws[327680 + n * 1024 + k] = f2b(W2[k * 128 + n]);
        }
    } else {
        int idx = (bx - 1792) * 256 + threadIdx.x;   // 0..2097151
        const float* s; u16* d; int i;
        if (idx < 1048576) { s = src; d = srcb; i = idx * 4; }
        else               { s = tgt; d = tgtb; i = (idx - 1048576) * 4; }
        f32x4 v = *(const f32x4*)(s + i);
        u16x4 o; o[0] = f2b(v[0]); o[1] = f2b(v[1]); o[2] = f2b(v[2]); o[3] = f2b(v[3]);
        *(u16x4*)(d + i) = o;
    }
}

// ---------------------------------------------------------------------------
// Workspace layout (u16 element offsets)
// ---------------------------------------------------------------------------
#define OFF_WQT  0u            // concat [WqT;WkT;WvT] 3x(128x128)
#define OFF_WMT  49152u
#define OFF_W1T  65536u
#define OFF_W2T  327680u
#define OFF_SRCB 458752u
#define OFF_TGTB 4653056u
#define OFF_QW   8847360u
#define OFF_KW   13041664u
#define OFF_VWT  17235968u
#define OFF_MSGB 21430272u     // bf16 msg, source-order
#define OFF_HID  25624576u     // bf16 32768x1024, ends 59179008

extern "C" void kernel_launch(void* const* d_in, const int* in_sizes, int n_in,
                              void* d_out, int out_size, void* d_ws, size_t ws_size,
                              hipStream_t stream)
{
    (void)in_sizes; (void)n_in; (void)out_size; (void)ws_size;
    const float* source = (const float*)d_in[0];
    const float* target = (const float*)d_in[1];
    const float* Wq = (const float*)d_in[2];
    const float* Wk = (const float*)d_in[3];
    const float* Wv = (const float*)d_in[4];
    const float* Wm = (const float*)d_in[5];
    const float* g1 = (const float*)d_in[6];
    const float* b1 = (const float*)d_in[7];
    const float* W1 = (const float*)d_in[8];
    const float* W2 = (const float*)d_in[9];
    const float* g2 = (const float*)d_in[10];
    const float* b2 = (const float*)d_in[11];
    u16* ws = (u16*)d_ws;
    float* out = (float*)d_out;

    prep_all<<<9984, 256, 0, stream>>>(Wq, Wk, Wv, Wm, W1, W2, source, target,
                                       ws, ws + OFF_SRCB, ws + OFF_TGTB);
    gemm_qkv<<<dim3(256, 3), 256, 0, stream>>>(
        ws + OFF_SRCB, ws + OFF_TGTB, ws + OFF_WQT,
        ws + OFF_QW, ws + OFF_KW, ws + OFF_VWT);
    attn_msg<<<512, 256, 0, stream>>>(
        ws + OFF_QW, ws + OFF_KW, ws + OFF_VWT, ws + OFF_WMT, g1, b1,
        ws + OFF_MSGB);
    gemm_ffn1<<<dim3(256, 8), 256, 0, stream>>>(
        ws + OFF_SRCB, ws + OFF_MSGB, ws + OFF_W1T, ws + OFF_HID);
    gemm_ffn2<<<512, 256, 0, stream>>>(
        ws + OFF_HID, ws + OFF_W2T, g2, b2, source, out);
}